// Round 16
// baseline (718.046 us; speedup 1.0000x reference)
//
#include <hip/hip_runtime.h>

#define N_NODES 50000
#define N_EDGES 400000
#define N_GRAPHS 64
#define EMB 64
#define H 128
#define EPS 1e-5f

#define NCH2 49            // dst chunks of 1024 nodes
#define NSLA 48            // partition slices

typedef __attribute__((ext_vector_type(8))) short bf16x8;
typedef __attribute__((ext_vector_type(4))) float f32x4;

__device__ __forceinline__ unsigned short f2b(float f) {
    unsigned int u = __builtin_bit_cast(unsigned int, f);
    unsigned int r = (u + 0x7fff + ((u >> 16) & 1)) >> 16;  // RNE
    return (unsigned short)r;
}

// ---------------- CSR build ----------------

__global__ void count_deg_kernel(const int* __restrict__ dst, int* __restrict__ deg) {
    int rel = blockIdx.y;
    int e = blockIdx.x * 256 + threadIdx.x;
    if (e < N_EDGES) atomicAdd(&deg[rel * N_NODES + dst[rel * N_EDGES + e]], 1);
}

__global__ void scan_kernel(const int* __restrict__ deg, int* __restrict__ row_ptr,
                            int* __restrict__ cur, int* __restrict__ gcur) {
    int rel = blockIdx.x;
    const int* d = deg + rel * N_NODES;
    int* rp = row_ptr + rel * (N_NODES + 1);
    int* cu = cur + rel * N_NODES;
    __shared__ int sm[1024];
    __shared__ int carry;
    if (threadIdx.x == 0) carry = 0;
    __syncthreads();
    for (int base = 0; base < N_NODES; base += 4096) {
        int i0 = base + (int)threadIdx.x * 4;
        int v[4];
        int s = 0;
#pragma unroll
        for (int k = 0; k < 4; k++) { v[k] = (i0 + k < N_NODES) ? d[i0 + k] : 0; s += v[k]; }
        sm[threadIdx.x] = s;
        __syncthreads();
        for (int off = 1; off < 1024; off <<= 1) {
            int t = (threadIdx.x >= off) ? sm[threadIdx.x - off] : 0;
            __syncthreads();
            sm[threadIdx.x] += t;
            __syncthreads();
        }
        int run = carry + sm[threadIdx.x] - s;
#pragma unroll
        for (int k = 0; k < 4; k++) {
            int i = i0 + k;
            if (i < N_NODES) {
                rp[i] = run;
                cu[i] = run;
                if ((i & 1023) == 0) gcur[rel * NCH2 + (i >> 10)] = run;
            }
            run += v[k];
        }
        __syncthreads();
        if (threadIdx.x == 1023) carry += sm[1023];
        __syncthreads();
    }
    if (threadIdx.x == 0) rp[N_NODES] = carry;
}

// Phase A: partition edges into dst-chunk-major staging buffer (contiguous runs)
__global__ __launch_bounds__(256) void partA_kernel(
        const int* __restrict__ src, const int* __restrict__ dst,
        int* __restrict__ gcur, unsigned long long* __restrict__ chunkbuf) {
    int rel = blockIdx.y;
    const int* ds = dst + (size_t)rel * N_EDGES;
    const int* ss = src + (size_t)rel * N_EDGES;
    unsigned long long* cb = chunkbuf + (size_t)rel * N_EDGES;
    __shared__ int cnt[NCH2];
    __shared__ int lcur[NCH2];
    int tid = threadIdx.x;
    if (tid < NCH2) cnt[tid] = 0;
    __syncthreads();
    for (int e = blockIdx.x * 256 + tid; e < N_EDGES; e += NSLA * 256)
        atomicAdd(&cnt[ds[e] >> 10], 1);
    __syncthreads();
    if (tid < NCH2) lcur[tid] = atomicAdd(&gcur[rel * NCH2 + tid], cnt[tid]);
    __syncthreads();
    for (int e = blockIdx.x * 256 + tid; e < N_EDGES; e += NSLA * 256) {
        int dn = ds[e], sn = ss[e];
        int idx = atomicAdd(&lcur[dn >> 10], 1);
        cb[idx] = ((unsigned long long)(unsigned)sn << 32) | (unsigned)dn;
    }
}

// Phase B: each chunk's region placed by 2 blocks
__global__ __launch_bounds__(256) void fillB_kernel(
        const int* __restrict__ row_ptr, const unsigned long long* __restrict__ chunkbuf,
        int* __restrict__ cur, int* __restrict__ edge_src) {
    int rel = blockIdx.y;
    int c = blockIdx.x >> 1, half = blockIdx.x & 1;
    const int* rp = row_ptr + rel * (N_NODES + 1);
    int lo = rp[c << 10];
    int hiN = min((c + 1) << 10, N_NODES);
    int hi = rp[hiN];
    const unsigned long long* cb = chunkbuf + (size_t)rel * N_EDGES;
    int* cu = cur + rel * N_NODES;
    int* es = edge_src + (size_t)rel * N_EDGES;
    for (int i = lo + half + 2 * (int)threadIdx.x; i < hi; i += 2 * 256) {
        unsigned long long pr = cb[i];
        int dn = (int)(pr & 0xffffffffu);
        int sn = (int)(pr >> 32);
        int pos = atomicAdd(&cu[dn], 1);
        es[pos] = sn;
    }
}

// sort each node's adjacency list by src
__global__ void sort_adj_kernel(const int* __restrict__ row_ptr, int* __restrict__ edge_src) {
    int i = blockIdx.x * 256 + threadIdx.x;
    if (i >= 3 * N_NODES) return;
    int rel = i / N_NODES, n = i - rel * N_NODES;
    const int* rp = row_ptr + rel * (N_NODES + 1);
    int* es = edge_src + rel * N_EDGES;
    int s0 = rp[n], s1 = rp[n + 1];
    for (int a = s0 + 1; a < s1; a++) {
        int key = es[a];
        int b = a - 1;
        while (b >= s0 && es[b] > key) { es[b + 1] = es[b]; b--; }
        es[b + 1] = key;
    }
}

// ---------------- Fused init: layer-1 weights + bf16 emb tables ----------------

__global__ void prep_init_kernel(const float* __restrict__ W1self, const float* __restrict__ W1neigh,
                                 unsigned short* __restrict__ Wbt1,
                                 const float* __restrict__ emb_h, const float* __restrict__ emb_p,
                                 const float* __restrict__ emb_hp,
                                 unsigned short* __restrict__ emb_bf) {
    if (blockIdx.x < 192) {
        int idx = blockIdx.x * 256 + threadIdx.x;
        int rel = idx / (H * 128), rem = idx % (H * 128);
        int c = rem / 128, k = rem % 128;
        float v = (k < 64) ? W1self[((size_t)rel * 64 + k) * H + c]
                           : W1neigh[((size_t)rel * 64 + (k - 64)) * H + c];
        Wbt1[idx] = f2b(v);
    } else {
        int i = (blockIdx.x - 192) * 256 + threadIdx.x;
        if (i >= 3 * 257 * EMB / 8) return;
        int rel = i / (257 * EMB / 8), j = i % (257 * EMB / 8);
        const float* emb = rel == 0 ? emb_h : (rel == 1 ? emb_p : emb_hp);
        const float* e = emb + (size_t)j * 8;
        unsigned short o[8];
#pragma unroll
        for (int k = 0; k < 8; k++) o[k] = f2b(e[k]);
        *(uint4*)&emb_bf[(size_t)rel * 257 * EMB + (size_t)j * 8] = *(uint4*)o;
    }
}

// ---------------- Layer-1 aggregation via emb tables (cache-resident) ----------------

__global__ __launch_bounds__(256) void aggregate1_kernel(
        const int* __restrict__ h_idx, const int* __restrict__ p_idx,
        const int* __restrict__ hp_idx,
        const unsigned short* __restrict__ emb_bf,
        const int* __restrict__ row_ptr, const int* __restrict__ edge_src,
        unsigned short* __restrict__ nmean) {
    const int TPN = 8;
    int rel = blockIdx.y;
    int node = blockIdx.x * 32 + threadIdx.x / TPN;
    int c8 = (threadIdx.x % TPN) * 8;
    if (node >= N_NODES) return;
    const int* idxarr = rel == 0 ? h_idx : (rel == 1 ? p_idx : hp_idx);
    const unsigned short* emb = emb_bf + (size_t)rel * 257 * EMB;
    const int* rp = row_ptr + rel * (N_NODES + 1);
    const int* es = edge_src + rel * N_EDGES;
    int s0 = rp[node], s1 = rp[node + 1];
    float acc[8];
#pragma unroll
    for (int j = 0; j < 8; j++) acc[j] = 0.f;

#define ACCUM(V)                                                                      \
    {                                                                                 \
        unsigned int w[4] = {(V).x, (V).y, (V).z, (V).w};                             \
        _Pragma("unroll") for (int j = 0; j < 4; j++) {                               \
            acc[2 * j] += __builtin_bit_cast(float, w[j] << 16);                      \
            acc[2 * j + 1] += __builtin_bit_cast(float, w[j] & 0xffff0000u);          \
        }                                                                             \
    }

    int e = s0;
    for (; e + 4 <= s1; e += 4) {
        int i0 = idxarr[es[e]], i1 = idxarr[es[e + 1]];
        int i2 = idxarr[es[e + 2]], i3 = idxarr[es[e + 3]];
        uint4 v0 = *(const uint4*)&emb[(size_t)i0 * EMB + c8];
        uint4 v1 = *(const uint4*)&emb[(size_t)i1 * EMB + c8];
        uint4 v2 = *(const uint4*)&emb[(size_t)i2 * EMB + c8];
        uint4 v3 = *(const uint4*)&emb[(size_t)i3 * EMB + c8];
        ACCUM(v0) ACCUM(v1) ACCUM(v2) ACCUM(v3)
    }
    for (; e < s1; e++) {
        uint4 v0 = *(const uint4*)&emb[(size_t)idxarr[es[e]] * EMB + c8];
        ACCUM(v0)
    }
    int deg = s1 - s0;
    float inv = 1.f / (float)max(deg, 1);
    unsigned short o[8];
#pragma unroll
    for (int j = 0; j < 8; j++)
        o[j] = (deg > 0) ? f2b(acc[j] * inv) : (unsigned short)0;
    *(uint4*)&nmean[((size_t)rel * N_NODES + node) * EMB + c8] = *(uint4*)o;
}

// ---------------- Layers 2-4 aggregation ----------------

template <bool FOLD>
__global__ __launch_bounds__(256) void aggregate_kernel(
        const unsigned short* __restrict__ x,
        const int* __restrict__ row_ptr, const int* __restrict__ edge_src,
        const float* __restrict__ st,
        unsigned short* __restrict__ nmean) {
    const int TPN = 16;
    int rel = blockIdx.y;
    int c8 = (threadIdx.x % TPN) * 8;
    int nloc = threadIdx.x / TPN;
    const int* rp = row_ptr + rel * (N_NODES + 1);
    const int* es = edge_src + rel * N_EDGES;
    const unsigned short* xr = x + (size_t)rel * N_NODES * H;

    float sj[8], tj[8];
    if (FOLD) {
#pragma unroll
        for (int j = 0; j < 8; j++) {
            sj[j] = st[rel * 2 * H + c8 + j];
            tj[j] = st[rel * 2 * H + H + c8 + j];
        }
    }

#pragma unroll
    for (int batch = 0; batch < 6; batch++) {
        int node = blockIdx.x * 96 + batch * 16 + nloc;
        if (node >= N_NODES) continue;
        int s0 = rp[node], s1 = rp[node + 1];
        float acc[8];
#pragma unroll
        for (int j = 0; j < 8; j++) acc[j] = 0.f;
        int e = s0;
        for (; e + 4 <= s1; e += 4) {
            int i0 = es[e], i1 = es[e + 1], i2 = es[e + 2], i3 = es[e + 3];
            uint4 v0 = *(const uint4*)&xr[(size_t)i0 * H + c8];
            uint4 v1 = *(const uint4*)&xr[(size_t)i1 * H + c8];
            uint4 v2 = *(const uint4*)&xr[(size_t)i2 * H + c8];
            uint4 v3 = *(const uint4*)&xr[(size_t)i3 * H + c8];
            ACCUM(v0) ACCUM(v1) ACCUM(v2) ACCUM(v3)
        }
        for (; e < s1; e++) {
            uint4 v0 = *(const uint4*)&xr[(size_t)es[e] * H + c8];
            ACCUM(v0)
        }
        int deg = s1 - s0;
        float inv = 1.f / (float)max(deg, 1);
        unsigned short o[8];
#pragma unroll
        for (int j = 0; j < 8; j++) {
            float m = acc[j] * inv;
            if (FOLD) m = sj[j] * m + tj[j];
            o[j] = (deg > 0) ? f2b(m) : (unsigned short)0;
        }
        *(uint4*)&nmean[((size_t)rel * N_NODES + node) * H + c8] = *(uint4*)o;
    }
#undef ACCUM
}

// ---- MFMA GEMM (barrier-light): B half-panel staged to LDS once per phase;
//      A fragments load directly from global (coalesced, no K-loop barriers).
//      hp = PReLU([x|nmean]@Wbt^T + b); fp32 col stats; readout fused. ----

template <int KX, bool G1, bool STORE>
__global__ __launch_bounds__(512) void gemm_kernel(
        const unsigned short* __restrict__ x,
        const unsigned short* __restrict__ nmean,
        const unsigned short* __restrict__ Wbt,
        const float* __restrict__ bias,
        const float* __restrict__ alpha,
        unsigned short* __restrict__ out,
        float* __restrict__ stats,
        const int* __restrict__ seg_all,
        float* __restrict__ gout,
        int layer,
        const unsigned short* __restrict__ embt,
        const int* __restrict__ h_idx, const int* __restrict__ p_idx,
        const int* __restrict__ hp_idx) {
    const int KTOT = 2 * KX;
    int rel = blockIdx.y;
    int row0 = blockIdx.x * 128;
    const unsigned short* xr = x + (size_t)rel * N_NODES * KX;
    const unsigned short* nm = nmean + (size_t)rel * N_NODES * KX;
    const unsigned short* W = Wbt + (size_t)rel * H * KTOT;
    unsigned short* o = out + (size_t)rel * N_NODES * H;

    __shared__ __align__(16) short Bl[128][KX + 8];   // padded: bank advance 4/row

    int tid = threadIdx.x;
    int lane = tid & 63;
    int wave = tid >> 6;          // 0..7
    int wr = wave >> 2;           // 0..1 (row half)
    int wcq = wave & 3;           // 0..3 (32-col strip)
    int l15 = lane & 15;
    int koff = (lane >> 4) * 8;

    f32x4 acc[4][2];
#pragma unroll
    for (int m = 0; m < 4; m++)
#pragma unroll
        for (int n = 0; n < 2; n++) acc[m][n] = (f32x4){0.f, 0.f, 0.f, 0.f};

    // per-thread A-fragment row offsets (clamped; invalid rows discarded in epilogue)
    size_t arow[4];
    int nid[4];
#pragma unroll
    for (int m = 0; m < 4; m++) {
        int r = row0 + wr * 64 + m * 16 + l15;
        int rc = min(r, N_NODES - 1);
        arow[m] = (size_t)rc * KX;
        if (G1) {
            const int* idxarr = rel == 0 ? h_idx : (rel == 1 ? p_idx : hp_idx);
            nid[m] = idxarr[rc];
        }
    }
    const unsigned short* et = G1 ? (embt + (size_t)rel * 257 * EMB) : nullptr;

#pragma unroll
    for (int ph = 0; ph < 2; ph++) {
        __syncthreads();   // safe to overwrite Bl
        {
            int c = tid >> 2;
            int s8 = (tid & 3) * 8;
#pragma unroll
            for (int q = 0; q < KX; q += 32)
                *(uint4*)&Bl[c][q + s8] = *(const uint4*)&W[(size_t)c * KTOT + ph * KX + q + s8];
        }
        __syncthreads();
        const unsigned short* As = (ph == 0) ? xr : nm;
        for (int kc = 0; kc < KX; kc += 32) {
            bf16x8 a[4], b[2];
#pragma unroll
            for (int m = 0; m < 4; m++) {
                if (G1 && ph == 0)
                    a[m] = *(const bf16x8*)&et[(size_t)nid[m] * EMB + kc + koff];
                else
                    a[m] = *(const bf16x8*)&As[arow[m] + kc + koff];
            }
#pragma unroll
            for (int n = 0; n < 2; n++)
                b[n] = *(const bf16x8*)&Bl[wcq * 32 + n * 16 + l15][kc + koff];
#pragma unroll
            for (int m = 0; m < 4; m++)
#pragma unroll
                for (int n = 0; n < 2; n++)
                    acc[m][n] = __builtin_amdgcn_mfma_f32_16x16x32_bf16(a[m], b[n], acc[m][n], 0, 0, 0);
        }
    }

    float bs[2], as_[2];
#pragma unroll
    for (int n = 0; n < 2; n++) {
        int col = wcq * 32 + n * 16 + l15;
        bs[n] = bias[rel * H + col];
        as_[n] = alpha[rel * H + col];
    }
    const int* sg = seg_all + rel * N_NODES;
    float csum[2] = {0.f, 0.f}, cssq[2] = {0.f, 0.f};
    int curg = -1;
    float run[2] = {0.f, 0.f};
    int rbase = row0 + wr * 64 + (lane >> 4) * 4;
#pragma unroll
    for (int m = 0; m < 4; m++) {
#pragma unroll
        for (int j = 0; j < 4; j++) {
            int r = rbase + m * 16 + j;
            if (r >= N_NODES) continue;
            int g = sg[r];
            if (g != curg) {
                if (curg >= 0) {
                    float* ob = gout + (size_t)curg * (3 * 4 * H) + rel * (4 * H) + layer * H + wcq * 32 + l15;
#pragma unroll
                    for (int n = 0; n < 2; n++) { atomicAdd(ob + n * 16, run[n]); run[n] = 0.f; }
                }
                curg = g;
            }
#pragma unroll
            for (int n = 0; n < 2; n++) {
                float v = acc[m][n][j] + bs[n];
                v = v > 0.f ? v : as_[n] * v;
                if (STORE) o[(size_t)r * H + wcq * 32 + n * 16 + l15] = f2b(v);
                csum[n] += v;
                cssq[n] += v * v;
                run[n] += v;
            }
        }
    }
    if (curg >= 0) {
        float* ob = gout + (size_t)curg * (3 * 4 * H) + rel * (4 * H) + layer * H + wcq * 32 + l15;
#pragma unroll
        for (int n = 0; n < 2; n++) atomicAdd(ob + n * 16, run[n]);
    }
    __syncthreads();
    float* smS = (float*)&Bl[0][0];   // 128 cols x 8 contributors x 2 arrays = 8 KB
    float* smQ = smS + 1024;
    int contrib = wr * 4 + (lane >> 4);
#pragma unroll
    for (int n = 0; n < 2; n++) {
        int col = wcq * 32 + n * 16 + l15;
        smS[col * 8 + contrib] = csum[n];
        smQ[col * 8 + contrib] = cssq[n];
    }
    __syncthreads();
    if (tid < 128) {
        float s = 0.f, q = 0.f;
#pragma unroll
        for (int i = 0; i < 8; i++) { s += smS[tid * 8 + i]; q += smQ[tid * 8 + i]; }
        atomicAdd(&stats[rel * 256 + tid], s);
        atomicAdd(&stats[rel * 256 + 128 + tid], q);
    }
}

// ---------------- BN stats -> affine (s,t); self-zero stats ----------------

__global__ void finalize_kernel(float* __restrict__ stats,
                                const float* __restrict__ gamma, const float* __restrict__ beta,
                                float* __restrict__ st) {
    int rel = blockIdx.x, c = threadIdx.x;
    const float invN = 1.f / N_NODES;
    float mu = stats[rel * 256 + c] * invN;
    float var = stats[rel * 256 + 128 + c] * invN - mu * mu;
    float s = gamma[rel * H + c] * rsqrtf(var + EPS);
    st[rel * 2 * H + c] = s;
    st[rel * 2 * H + H + c] = beta[rel * H + c] - mu * s;
    stats[rel * 256 + c] = 0.f;
    stats[rel * 256 + 128 + c] = 0.f;
}

// ---------------- Weight prep (layers 2-4) ----------------

__global__ void prep_kernel(const float* __restrict__ Wself, const float* __restrict__ Wneigh,
                            const float* __restrict__ b, const float* __restrict__ st,
                            unsigned short* __restrict__ Wbt, float* __restrict__ biasp) {
    if (blockIdx.x < 384) {
        int idx = blockIdx.x * 256 + threadIdx.x;
        int rel = idx / (H * 256), rem = idx % (H * 256);
        int c = rem / 256, k = rem % 256;
        float v;
        if (k < 128) v = st[rel * 2 * H + k] * Wself[((size_t)rel * H + k) * H + c];
        else         v = Wneigh[((size_t)rel * H + (k - 128)) * H + c];
        Wbt[idx] = f2b(v);
    } else if (threadIdx.x < H) {
        int rel = blockIdx.x - 384, c = threadIdx.x;
        const float* t = st + rel * 2 * H + H;
        float s = b[rel * H + c];
        for (int k = 0; k < H; k++) s += t[k] * Wself[((size_t)rel * H + k) * H + c];
        biasp[rel * H + c] = s;
    }
}

// ---------------- Final: mean + BN affine ----------------

__global__ void scale_out_kernel(float* __restrict__ out, const int* __restrict__ seg,
                                 const float* __restrict__ st_all) {
    int i = blockIdx.x * 256 + threadIdx.x;
    if (i >= N_GRAPHS * 3 * 4 * H) return;
    int g = i / (3 * 4 * H), k = i % (3 * 4 * H);
    int rel = k / (4 * H), rem = k % (4 * H), layer = rem / H, c = rem % H;
    const int* sg = seg + rel * N_NODES;
    int lo = 0, hi = N_NODES;
    while (lo < hi) { int m = (lo + hi) >> 1; if (sg[m] < g) lo = m + 1; else hi = m; }
    int start = lo;
    hi = N_NODES;
    while (lo < hi) { int m = (lo + hi) >> 1; if (sg[m] <= g) lo = m + 1; else hi = m; }
    int cnt = lo - start;
    float mean = out[i] / (float)max(cnt, 1);
    const float* st = st_all + ((size_t)layer * 3 + rel) * 2 * H;
    out[i] = st[c] * mean + st[H + c];
}

// ---------------- Orchestration ----------------

extern "C" void kernel_launch(void* const* d_in, const int* in_sizes, int n_in,
                              void* d_out, int out_size, void* d_ws, size_t ws_size,
                              hipStream_t stream) {
    const int* h_idx = (const int*)d_in[0];
    const int* p_idx = (const int*)d_in[1];
    const int* hp_idx = (const int*)d_in[2];
    const int* src = (const int*)d_in[3];
    const int* dst = (const int*)d_in[4];
    const int* seg = (const int*)d_in[5];
    const float* emb_h = (const float*)d_in[6];
    const float* emb_p = (const float*)d_in[7];
    const float* emb_hp = (const float*)d_in[8];
    const float* W1_self = (const float*)d_in[9];
    const float* W1_neigh = (const float*)d_in[10];
    const float* b1 = (const float*)d_in[11];
    const float* a1 = (const float*)d_in[12];
    const float* gamma1 = (const float*)d_in[13];
    const float* beta1 = (const float*)d_in[14];
    const float* W_self = (const float*)d_in[15];
    const float* W_neigh = (const float*)d_in[16];
    const float* b = (const float*)d_in[17];
    const float* a = (const float*)d_in[18];
    const float* gamma = (const float*)d_in[19];
    const float* beta = (const float*)d_in[20];
    float* out = (float*)d_out;

    // workspace
    char* p = (char*)d_ws;
    unsigned short* hpA = (unsigned short*)p; p += (size_t)3 * N_NODES * H * 2;
    unsigned short* hpB = (unsigned short*)p; p += (size_t)3 * N_NODES * H * 2;
    unsigned short* Wbt1 = (unsigned short*)p; p += (size_t)3 * H * 128 * 2;
    unsigned short* Wbt = (unsigned short*)p; p += (size_t)3 * H * 256 * 2;
    unsigned short* emb_bf = (unsigned short*)p; p += (size_t)3 * 257 * EMB * 2;
    float* biasp = (float*)p; p += 3 * H * sizeof(float);
    float* st_all = (float*)p; p += 4 * 3 * 2 * H * sizeof(float);
    float* stats = (float*)p; p += 3 * 256 * sizeof(float);
    int* deg = (int*)p; p += (size_t)3 * N_NODES * 4;
    int* row_ptr = (int*)p; p += (size_t)3 * (N_NODES + 1) * 4;
    int* cur = (int*)p; p += (size_t)3 * N_NODES * 4;
    int* gcur = (int*)p; p += (size_t)3 * NCH2 * 4;
    int* edge_src = (int*)p; p += (size_t)3 * N_EDGES * 4;
    unsigned long long* chunkbuf = (unsigned long long*)p; p += (size_t)3 * N_EDGES * 8;

    hipMemsetAsync(out, 0, (size_t)N_GRAPHS * 3 * 4 * H * sizeof(float), stream);
    hipMemsetAsync(stats, 0, 3 * 256 * 4, stream);

    // CSR build: count -> scan(+chunk cursors) -> partition -> place -> sort
    hipMemsetAsync(deg, 0, (size_t)3 * N_NODES * 4, stream);
    dim3 eb((N_EDGES + 255) / 256, 3);
    count_deg_kernel<<<eb, 256, 0, stream>>>(dst, deg);
    scan_kernel<<<3, 1024, 0, stream>>>(deg, row_ptr, cur, gcur);
    partA_kernel<<<dim3(NSLA, 3), 256, 0, stream>>>(src, dst, gcur, chunkbuf);
    fillB_kernel<<<dim3(2 * NCH2, 3), 256, 0, stream>>>(row_ptr, chunkbuf, cur, edge_src);
    sort_adj_kernel<<<(3 * N_NODES + 255) / 256, 256, 0, stream>>>(row_ptr, edge_src);

    prep_init_kernel<<<217, 256, 0, stream>>>(W1_self, W1_neigh, Wbt1,
                                              emb_h, emb_p, emb_hp, emb_bf);

    dim3 gemm_grid((N_NODES + 127) / 128, 3);
    dim3 agg_grid((N_NODES + 95) / 96, 3);

    // ---- layer 1 (K = 64; nmean ld=64 in hpB via emb-table gather; out hpA) ----
    aggregate1_kernel<<<dim3((N_NODES + 31) / 32, 3), 256, 0, stream>>>(
        h_idx, p_idx, hp_idx, emb_bf, row_ptr, edge_src, hpB);
    gemm_kernel<64, true, true><<<gemm_grid, 512, 0, stream>>>(
        emb_bf /*unused*/, hpB, Wbt1, b1, a1, hpA, stats, seg, out, 0,
        emb_bf, h_idx, p_idx, hp_idx);
    finalize_kernel<<<3, H, 0, stream>>>(stats, gamma1, beta1, st_all);

    // ---- layers 2-4 (K = 128; out aliases nmean; last layer skips hp store) ----
    unsigned short* xin = hpA;
    unsigned short* xout = hpB;
    for (int l = 0; l < 3; l++) {
        const float* st_prev = st_all + (size_t)l * 3 * 2 * H;
        prep_kernel<<<387, 256, 0, stream>>>(
            W_self + (size_t)l * 3 * H * H, W_neigh + (size_t)l * 3 * H * H,
            b + (size_t)l * 3 * H, st_prev, Wbt, biasp);
        aggregate_kernel<true><<<agg_grid, 256, 0, stream>>>(
            xin, row_ptr, edge_src, st_prev, xout);
        if (l < 2)
            gemm_kernel<128, false, true><<<gemm_grid, 512, 0, stream>>>(
                xin, xout, Wbt, biasp, a + (size_t)l * 3 * H, xout, stats, seg, out, l + 1,
                nullptr, nullptr, nullptr, nullptr);
        else
            gemm_kernel<128, false, false><<<gemm_grid, 512, 0, stream>>>(
                xin, xout, Wbt, biasp, a + (size_t)l * 3 * H, xout, stats, seg, out, l + 1,
                nullptr, nullptr, nullptr, nullptr);
        finalize_kernel<<<3, H, 0, stream>>>(
            stats, gamma + (size_t)l * 3 * H, beta + (size_t)l * 3 * H,
            st_all + (size_t)(l + 1) * 3 * 2 * H);
        unsigned short* t = xin; xin = xout; xout = t;
    }

    scale_out_kernel<<<(N_GRAPHS * 3 * 4 * H + 255) / 256, 256, 0, stream>>>(out, seg, st_all);
}

// Round 17
// 598.638 us; speedup vs baseline: 1.1995x; 1.1995x over previous
//
#include <hip/hip_runtime.h>

#define N_NODES 50000
#define N_EDGES 400000
#define N_GRAPHS 64
#define EMB 64
#define H 128
#define EPS 1e-5f

#define NCH2 49            // dst chunks of 1024 nodes
#define NSLA 48            // partition slices
#define SREP 16            // stats replicas
#define GREP 4             // gout replicas
#define GSZ (N_GRAPHS * 3 * 4 * H)

typedef __attribute__((ext_vector_type(8))) short bf16x8;
typedef __attribute__((ext_vector_type(4))) float f32x4;

__device__ __forceinline__ unsigned short f2b(float f) {
    unsigned int u = __builtin_bit_cast(unsigned int, f);
    unsigned int r = (u + 0x7fff + ((u >> 16) & 1)) >> 16;  // RNE
    return (unsigned short)r;
}

// ---------------- CSR build ----------------

__global__ void count_deg_kernel(const int* __restrict__ dst, int* __restrict__ deg) {
    int rel = blockIdx.y;
    int e = blockIdx.x * 256 + threadIdx.x;
    if (e < N_EDGES) atomicAdd(&deg[rel * N_NODES + dst[rel * N_EDGES + e]], 1);
}

__global__ void scan_kernel(const int* __restrict__ deg, int* __restrict__ row_ptr,
                            int* __restrict__ cur, int* __restrict__ gcur) {
    int rel = blockIdx.x;
    const int* d = deg + rel * N_NODES;
    int* rp = row_ptr + rel * (N_NODES + 1);
    int* cu = cur + rel * N_NODES;
    __shared__ int sm[1024];
    __shared__ int carry;
    if (threadIdx.x == 0) carry = 0;
    __syncthreads();
    for (int base = 0; base < N_NODES; base += 4096) {
        int i0 = base + (int)threadIdx.x * 4;
        int v[4];
        int s = 0;
#pragma unroll
        for (int k = 0; k < 4; k++) { v[k] = (i0 + k < N_NODES) ? d[i0 + k] : 0; s += v[k]; }
        sm[threadIdx.x] = s;
        __syncthreads();
        for (int off = 1; off < 1024; off <<= 1) {
            int t = (threadIdx.x >= off) ? sm[threadIdx.x - off] : 0;
            __syncthreads();
            sm[threadIdx.x] += t;
            __syncthreads();
        }
        int run = carry + sm[threadIdx.x] - s;
#pragma unroll
        for (int k = 0; k < 4; k++) {
            int i = i0 + k;
            if (i < N_NODES) {
                rp[i] = run;
                cu[i] = run;
                if ((i & 1023) == 0) gcur[rel * NCH2 + (i >> 10)] = run;
            }
            run += v[k];
        }
        __syncthreads();
        if (threadIdx.x == 1023) carry += sm[1023];
        __syncthreads();
    }
    if (threadIdx.x == 0) rp[N_NODES] = carry;
}

// Phase A: partition edges into dst-chunk-major staging buffer (contiguous runs)
__global__ __launch_bounds__(256) void partA_kernel(
        const int* __restrict__ src, const int* __restrict__ dst,
        int* __restrict__ gcur, unsigned long long* __restrict__ chunkbuf) {
    int rel = blockIdx.y;
    const int* ds = dst + (size_t)rel * N_EDGES;
    const int* ss = src + (size_t)rel * N_EDGES;
    unsigned long long* cb = chunkbuf + (size_t)rel * N_EDGES;
    __shared__ int cnt[NCH2];
    __shared__ int lcur[NCH2];
    int tid = threadIdx.x;
    if (tid < NCH2) cnt[tid] = 0;
    __syncthreads();
    for (int e = blockIdx.x * 256 + tid; e < N_EDGES; e += NSLA * 256)
        atomicAdd(&cnt[ds[e] >> 10], 1);
    __syncthreads();
    if (tid < NCH2) lcur[tid] = atomicAdd(&gcur[rel * NCH2 + tid], cnt[tid]);
    __syncthreads();
    for (int e = blockIdx.x * 256 + tid; e < N_EDGES; e += NSLA * 256) {
        int dn = ds[e], sn = ss[e];
        int idx = atomicAdd(&lcur[dn >> 10], 1);
        cb[idx] = ((unsigned long long)(unsigned)sn << 32) | (unsigned)dn;
    }
}

// Phase B: each chunk's region placed by 2 blocks
__global__ __launch_bounds__(256) void fillB_kernel(
        const int* __restrict__ row_ptr, const unsigned long long* __restrict__ chunkbuf,
        int* __restrict__ cur, int* __restrict__ edge_src) {
    int rel = blockIdx.y;
    int c = blockIdx.x >> 1, half = blockIdx.x & 1;
    const int* rp = row_ptr + rel * (N_NODES + 1);
    int lo = rp[c << 10];
    int hiN = min((c + 1) << 10, N_NODES);
    int hi = rp[hiN];
    const unsigned long long* cb = chunkbuf + (size_t)rel * N_EDGES;
    int* cu = cur + rel * N_NODES;
    int* es = edge_src + (size_t)rel * N_EDGES;
    for (int i = lo + half + 2 * (int)threadIdx.x; i < hi; i += 2 * 256) {
        unsigned long long pr = cb[i];
        int dn = (int)(pr & 0xffffffffu);
        int sn = (int)(pr >> 32);
        int pos = atomicAdd(&cu[dn], 1);
        es[pos] = sn;
    }
}

// sort each node's adjacency list by src
__global__ void sort_adj_kernel(const int* __restrict__ row_ptr, int* __restrict__ edge_src) {
    int i = blockIdx.x * 256 + threadIdx.x;
    if (i >= 3 * N_NODES) return;
    int rel = i / N_NODES, n = i - rel * N_NODES;
    const int* rp = row_ptr + rel * (N_NODES + 1);
    int* es = edge_src + rel * N_EDGES;
    int s0 = rp[n], s1 = rp[n + 1];
    for (int a = s0 + 1; a < s1; a++) {
        int key = es[a];
        int b = a - 1;
        while (b >= s0 && es[b] > key) { es[b + 1] = es[b]; b--; }
        es[b + 1] = key;
    }
}

// ---------------- Fused init: layer-1 weights + bf16 emb tables ----------------

__global__ void prep_init_kernel(const float* __restrict__ W1self, const float* __restrict__ W1neigh,
                                 unsigned short* __restrict__ Wbt1,
                                 const float* __restrict__ emb_h, const float* __restrict__ emb_p,
                                 const float* __restrict__ emb_hp,
                                 unsigned short* __restrict__ emb_bf) {
    if (blockIdx.x < 192) {
        int idx = blockIdx.x * 256 + threadIdx.x;
        int rel = idx / (H * 128), rem = idx % (H * 128);
        int c = rem / 128, k = rem % 128;
        float v = (k < 64) ? W1self[((size_t)rel * 64 + k) * H + c]
                           : W1neigh[((size_t)rel * 64 + (k - 64)) * H + c];
        Wbt1[idx] = f2b(v);
    } else {
        int i = (blockIdx.x - 192) * 256 + threadIdx.x;
        if (i >= 3 * 257 * EMB / 8) return;
        int rel = i / (257 * EMB / 8), j = i % (257 * EMB / 8);
        const float* emb = rel == 0 ? emb_h : (rel == 1 ? emb_p : emb_hp);
        const float* e = emb + (size_t)j * 8;
        unsigned short o[8];
#pragma unroll
        for (int k = 0; k < 8; k++) o[k] = f2b(e[k]);
        *(uint4*)&emb_bf[(size_t)rel * 257 * EMB + (size_t)j * 8] = *(uint4*)o;
    }
}

// ---------------- Layer-1 aggregation via emb tables (cache-resident) ----------------

__global__ __launch_bounds__(256) void aggregate1_kernel(
        const int* __restrict__ h_idx, const int* __restrict__ p_idx,
        const int* __restrict__ hp_idx,
        const unsigned short* __restrict__ emb_bf,
        const int* __restrict__ row_ptr, const int* __restrict__ edge_src,
        unsigned short* __restrict__ nmean) {
    const int TPN = 8;
    int rel = blockIdx.y;
    int node = blockIdx.x * 32 + threadIdx.x / TPN;
    int c8 = (threadIdx.x % TPN) * 8;
    if (node >= N_NODES) return;
    const int* idxarr = rel == 0 ? h_idx : (rel == 1 ? p_idx : hp_idx);
    const unsigned short* emb = emb_bf + (size_t)rel * 257 * EMB;
    const int* rp = row_ptr + rel * (N_NODES + 1);
    const int* es = edge_src + rel * N_EDGES;
    int s0 = rp[node], s1 = rp[node + 1];
    float acc[8];
#pragma unroll
    for (int j = 0; j < 8; j++) acc[j] = 0.f;

#define ACCUM(V)                                                                      \
    {                                                                                 \
        unsigned int w[4] = {(V).x, (V).y, (V).z, (V).w};                             \
        _Pragma("unroll") for (int j = 0; j < 4; j++) {                               \
            acc[2 * j] += __builtin_bit_cast(float, w[j] << 16);                      \
            acc[2 * j + 1] += __builtin_bit_cast(float, w[j] & 0xffff0000u);          \
        }                                                                             \
    }

    int e = s0;
    for (; e + 4 <= s1; e += 4) {
        int i0 = idxarr[es[e]], i1 = idxarr[es[e + 1]];
        int i2 = idxarr[es[e + 2]], i3 = idxarr[es[e + 3]];
        uint4 v0 = *(const uint4*)&emb[(size_t)i0 * EMB + c8];
        uint4 v1 = *(const uint4*)&emb[(size_t)i1 * EMB + c8];
        uint4 v2 = *(const uint4*)&emb[(size_t)i2 * EMB + c8];
        uint4 v3 = *(const uint4*)&emb[(size_t)i3 * EMB + c8];
        ACCUM(v0) ACCUM(v1) ACCUM(v2) ACCUM(v3)
    }
    for (; e < s1; e++) {
        uint4 v0 = *(const uint4*)&emb[(size_t)idxarr[es[e]] * EMB + c8];
        ACCUM(v0)
    }
    int deg = s1 - s0;
    float inv = 1.f / (float)max(deg, 1);
    unsigned short o[8];
#pragma unroll
    for (int j = 0; j < 8; j++)
        o[j] = (deg > 0) ? f2b(acc[j] * inv) : (unsigned short)0;
    *(uint4*)&nmean[((size_t)rel * N_NODES + node) * EMB + c8] = *(uint4*)o;
}

// ---------------- Layers 2-4 aggregation ----------------

template <bool FOLD>
__global__ __launch_bounds__(256) void aggregate_kernel(
        const unsigned short* __restrict__ x,
        const int* __restrict__ row_ptr, const int* __restrict__ edge_src,
        const float* __restrict__ st,
        unsigned short* __restrict__ nmean) {
    const int TPN = 16;
    int rel = blockIdx.y;
    int c8 = (threadIdx.x % TPN) * 8;
    int nloc = threadIdx.x / TPN;
    const int* rp = row_ptr + rel * (N_NODES + 1);
    const int* es = edge_src + rel * N_EDGES;
    const unsigned short* xr = x + (size_t)rel * N_NODES * H;

    float sj[8], tj[8];
    if (FOLD) {
#pragma unroll
        for (int j = 0; j < 8; j++) {
            sj[j] = st[rel * 2 * H + c8 + j];
            tj[j] = st[rel * 2 * H + H + c8 + j];
        }
    }

#pragma unroll
    for (int batch = 0; batch < 6; batch++) {
        int node = blockIdx.x * 96 + batch * 16 + nloc;
        if (node >= N_NODES) continue;
        int s0 = rp[node], s1 = rp[node + 1];
        float acc[8];
#pragma unroll
        for (int j = 0; j < 8; j++) acc[j] = 0.f;
        int e = s0;
        for (; e + 4 <= s1; e += 4) {
            int i0 = es[e], i1 = es[e + 1], i2 = es[e + 2], i3 = es[e + 3];
            uint4 v0 = *(const uint4*)&xr[(size_t)i0 * H + c8];
            uint4 v1 = *(const uint4*)&xr[(size_t)i1 * H + c8];
            uint4 v2 = *(const uint4*)&xr[(size_t)i2 * H + c8];
            uint4 v3 = *(const uint4*)&xr[(size_t)i3 * H + c8];
            ACCUM(v0) ACCUM(v1) ACCUM(v2) ACCUM(v3)
        }
        for (; e < s1; e++) {
            uint4 v0 = *(const uint4*)&xr[(size_t)es[e] * H + c8];
            ACCUM(v0)
        }
        int deg = s1 - s0;
        float inv = 1.f / (float)max(deg, 1);
        unsigned short o[8];
#pragma unroll
        for (int j = 0; j < 8; j++) {
            float m = acc[j] * inv;
            if (FOLD) m = sj[j] * m + tj[j];
            o[j] = (deg > 0) ? f2b(m) : (unsigned short)0;
        }
        *(uint4*)&nmean[((size_t)rel * N_NODES + node) * H + c8] = *(uint4*)o;
    }
#undef ACCUM
}

// ---- MFMA GEMM (512 threads, 8 waves, LDS-staged; proven r15 structure):
//      hp = PReLU([x|nmean]@Wbt^T + b); fp32 col stats (16-way striped);
//      per-graph readout fused (4-way striped); STORE=false skips hp write. ----

template <int KX, bool G1, bool STORE>
__global__ __launch_bounds__(512) void gemm_kernel(
        const unsigned short* __restrict__ x,
        const unsigned short* __restrict__ nmean,
        const unsigned short* __restrict__ Wbt,
        const float* __restrict__ bias,
        const float* __restrict__ alpha,
        unsigned short* __restrict__ out,
        float* __restrict__ statsR,               // [SREP][3][256]
        const int* __restrict__ seg_all,
        float* __restrict__ goutR,                // [GREP][GSZ]
        int layer,
        const unsigned short* __restrict__ embt,
        const int* __restrict__ h_idx, const int* __restrict__ p_idx,
        const int* __restrict__ hp_idx) {
    const int KTOT = 2 * KX;
    int rel = blockIdx.y;
    int row0 = blockIdx.x * 128;
    const unsigned short* xr = x + (size_t)rel * N_NODES * KX;
    const unsigned short* nm = nmean + (size_t)rel * N_NODES * KX;
    const unsigned short* W = Wbt + (size_t)rel * H * KTOT;
    unsigned short* o = out + (size_t)rel * N_NODES * H;
    float* stats = statsR + (size_t)(blockIdx.x & (SREP - 1)) * 768;
    float* gout = goutR + (size_t)(blockIdx.x & (GREP - 1)) * GSZ;

    __shared__ __align__(16) short At[128][40];
    __shared__ __align__(16) short Bt[128][40];

    int tid = threadIdx.x;
    int lane = tid & 63;
    int wave = tid >> 6;          // 0..7
    int wr = wave >> 2;           // 0..1 (row half)
    int wcq = wave & 3;           // 0..3 (32-col strip)
    int l15 = lane & 15;
    int koff = (lane >> 4) * 8;

    f32x4 acc[4][2];
#pragma unroll
    for (int m = 0; m < 4; m++)
#pragma unroll
        for (int n = 0; n < 2; n++) acc[m][n] = (f32x4){0.f, 0.f, 0.f, 0.f};

    int seg = tid & 3;
    int rloc = tid >> 2;          // 0..127 (one staged row per thread)

    int nid0 = 0;
    if (G1) {
        const int* idxarr = rel == 0 ? h_idx : (rel == 1 ? p_idx : hp_idx);
        if (row0 + rloc < N_NODES) nid0 = idxarr[row0 + rloc];
    }
    const unsigned short* et = G1 ? (embt + (size_t)rel * 257 * EMB) : nullptr;

    for (int kc = 0; kc < KTOT; kc += 32) {
        const bool selfh = kc < KX;
        const unsigned short* Asrc = selfh ? xr : nm;
        int kb = selfh ? kc : kc - KX;
        {
            int gr = row0 + rloc;
            uint4 v = make_uint4(0u, 0u, 0u, 0u);
            if (gr < N_NODES) {
                if (G1 && selfh) v = *(const uint4*)&et[(size_t)nid0 * EMB + kb + seg * 8];
                else             v = *(const uint4*)&Asrc[(size_t)gr * KX + kb + seg * 8];
            }
            *(uint4*)&At[rloc][seg * 8] = v;
            *(uint4*)&Bt[rloc][seg * 8] = *(const uint4*)&W[(size_t)rloc * KTOT + kc + seg * 8];
        }
        __syncthreads();
        bf16x8 a[4], b[2];
#pragma unroll
        for (int m = 0; m < 4; m++) a[m] = *(const bf16x8*)&At[wr * 64 + m * 16 + l15][koff];
#pragma unroll
        for (int n = 0; n < 2; n++) b[n] = *(const bf16x8*)&Bt[wcq * 32 + n * 16 + l15][koff];
#pragma unroll
        for (int m = 0; m < 4; m++)
#pragma unroll
            for (int n = 0; n < 2; n++)
                acc[m][n] = __builtin_amdgcn_mfma_f32_16x16x32_bf16(a[m], b[n], acc[m][n], 0, 0, 0);
        __syncthreads();
    }

    float bs[2], as_[2];
#pragma unroll
    for (int n = 0; n < 2; n++) {
        int col = wcq * 32 + n * 16 + l15;
        bs[n] = bias[rel * H + col];
        as_[n] = alpha[rel * H + col];
    }
    const int* sg = seg_all + rel * N_NODES;
    float csum[2] = {0.f, 0.f}, cssq[2] = {0.f, 0.f};
    int curg = -1;
    float run[2] = {0.f, 0.f};
    int rbase = row0 + wr * 64 + (lane >> 4) * 4;
#pragma unroll
    for (int m = 0; m < 4; m++) {
#pragma unroll
        for (int j = 0; j < 4; j++) {
            int r = rbase + m * 16 + j;
            if (r >= N_NODES) continue;
            int g = sg[r];
            if (g != curg) {
                if (curg >= 0) {
                    float* ob = gout + (size_t)curg * (3 * 4 * H) + rel * (4 * H) + layer * H + wcq * 32 + l15;
#pragma unroll
                    for (int n = 0; n < 2; n++) { atomicAdd(ob + n * 16, run[n]); run[n] = 0.f; }
                }
                curg = g;
            }
#pragma unroll
            for (int n = 0; n < 2; n++) {
                float v = acc[m][n][j] + bs[n];
                v = v > 0.f ? v : as_[n] * v;
                if (STORE) o[(size_t)r * H + wcq * 32 + n * 16 + l15] = f2b(v);
                csum[n] += v;
                cssq[n] += v * v;
                run[n] += v;
            }
        }
    }
    if (curg >= 0) {
        float* ob = gout + (size_t)curg * (3 * 4 * H) + rel * (4 * H) + layer * H + wcq * 32 + l15;
#pragma unroll
        for (int n = 0; n < 2; n++) atomicAdd(ob + n * 16, run[n]);
    }
    __syncthreads();
    float* smS = (float*)&At[0][0];   // 128 cols x 8 contributors = 4 KB
    float* smQ = (float*)&Bt[0][0];
    int contrib = wr * 4 + (lane >> 4);
#pragma unroll
    for (int n = 0; n < 2; n++) {
        int col = wcq * 32 + n * 16 + l15;
        smS[col * 8 + contrib] = csum[n];
        smQ[col * 8 + contrib] = cssq[n];
    }
    __syncthreads();
    if (tid < 128) {
        float s = 0.f, q = 0.f;
#pragma unroll
        for (int i = 0; i < 8; i++) { s += smS[tid * 8 + i]; q += smQ[tid * 8 + i]; }
        atomicAdd(&stats[rel * 256 + tid], s);
        atomicAdd(&stats[rel * 256 + 128 + tid], q);
    }
}

// ---------------- BN stats (sum 16 replicas) -> affine (s,t); zero replicas ----------------

__global__ void finalize_kernel(float* __restrict__ statsR,
                                const float* __restrict__ gamma, const float* __restrict__ beta,
                                float* __restrict__ st) {
    int rel = blockIdx.x, c = threadIdx.x;
    float sum = 0.f, ssq = 0.f;
#pragma unroll
    for (int k = 0; k < SREP; k++) {
        sum += statsR[(size_t)k * 768 + rel * 256 + c];
        ssq += statsR[(size_t)k * 768 + rel * 256 + 128 + c];
        statsR[(size_t)k * 768 + rel * 256 + c] = 0.f;
        statsR[(size_t)k * 768 + rel * 256 + 128 + c] = 0.f;
    }
    const float invN = 1.f / N_NODES;
    float mu = sum * invN;
    float var = ssq * invN - mu * mu;
    float s = gamma[rel * H + c] * rsqrtf(var + EPS);
    st[rel * 2 * H + c] = s;
    st[rel * 2 * H + H + c] = beta[rel * H + c] - mu * s;
}

// ---------------- Weight prep (layers 2-4) ----------------

__global__ void prep_kernel(const float* __restrict__ Wself, const float* __restrict__ Wneigh,
                            const float* __restrict__ b, const float* __restrict__ st,
                            unsigned short* __restrict__ Wbt, float* __restrict__ biasp) {
    if (blockIdx.x < 384) {
        int idx = blockIdx.x * 256 + threadIdx.x;
        int rel = idx / (H * 256), rem = idx % (H * 256);
        int c = rem / 256, k = rem % 256;
        float v;
        if (k < 128) v = st[rel * 2 * H + k] * Wself[((size_t)rel * H + k) * H + c];
        else         v = Wneigh[((size_t)rel * H + (k - 128)) * H + c];
        Wbt[idx] = f2b(v);
    } else if (threadIdx.x < H) {
        int rel = blockIdx.x - 384, c = threadIdx.x;
        const float* t = st + rel * 2 * H + H;
        float s = b[rel * H + c];
        for (int k = 0; k < H; k++) s += t[k] * Wself[((size_t)rel * H + k) * H + c];
        biasp[rel * H + c] = s;
    }
}

// ---------------- Final: sum gout replicas, mean + BN affine ----------------

__global__ void scale_out_kernel(float* __restrict__ out, const float* __restrict__ goutR,
                                 const int* __restrict__ seg,
                                 const float* __restrict__ st_all) {
    int i = blockIdx.x * 256 + threadIdx.x;
    if (i >= GSZ) return;
    int g = i / (3 * 4 * H), k = i % (3 * 4 * H);
    int rel = k / (4 * H), rem = k % (4 * H), layer = rem / H, c = rem % H;
    const int* sg = seg + rel * N_NODES;
    int lo = 0, hi = N_NODES;
    while (lo < hi) { int m = (lo + hi) >> 1; if (sg[m] < g) lo = m + 1; else hi = m; }
    int start = lo;
    hi = N_NODES;
    while (lo < hi) { int m = (lo + hi) >> 1; if (sg[m] <= g) lo = m + 1; else hi = m; }
    int cnt = lo - start;
    float sum = 0.f;
#pragma unroll
    for (int r = 0; r < GREP; r++) sum += goutR[(size_t)r * GSZ + i];
    float mean = sum / (float)max(cnt, 1);
    const float* st = st_all + ((size_t)layer * 3 + rel) * 2 * H;
    out[i] = st[c] * mean + st[H + c];
}

// ---------------- Orchestration ----------------

extern "C" void kernel_launch(void* const* d_in, const int* in_sizes, int n_in,
                              void* d_out, int out_size, void* d_ws, size_t ws_size,
                              hipStream_t stream) {
    const int* h_idx = (const int*)d_in[0];
    const int* p_idx = (const int*)d_in[1];
    const int* hp_idx = (const int*)d_in[2];
    const int* src = (const int*)d_in[3];
    const int* dst = (const int*)d_in[4];
    const int* seg = (const int*)d_in[5];
    const float* emb_h = (const float*)d_in[6];
    const float* emb_p = (const float*)d_in[7];
    const float* emb_hp = (const float*)d_in[8];
    const float* W1_self = (const float*)d_in[9];
    const float* W1_neigh = (const float*)d_in[10];
    const float* b1 = (const float*)d_in[11];
    const float* a1 = (const float*)d_in[12];
    const float* gamma1 = (const float*)d_in[13];
    const float* beta1 = (const float*)d_in[14];
    const float* W_self = (const float*)d_in[15];
    const float* W_neigh = (const float*)d_in[16];
    const float* b = (const float*)d_in[17];
    const float* a = (const float*)d_in[18];
    const float* gamma = (const float*)d_in[19];
    const float* beta = (const float*)d_in[20];
    float* out = (float*)d_out;

    // workspace
    char* p = (char*)d_ws;
    unsigned short* hpA = (unsigned short*)p; p += (size_t)3 * N_NODES * H * 2;
    unsigned short* hpB = (unsigned short*)p; p += (size_t)3 * N_NODES * H * 2;
    unsigned short* Wbt1 = (unsigned short*)p; p += (size_t)3 * H * 128 * 2;
    unsigned short* Wbt = (unsigned short*)p; p += (size_t)3 * H * 256 * 2;
    unsigned short* emb_bf = (unsigned short*)p; p += (size_t)3 * 257 * EMB * 2;
    float* biasp = (float*)p; p += 3 * H * sizeof(float);
    float* st_all = (float*)p; p += 4 * 3 * 2 * H * sizeof(float);
    float* statsR = (float*)p; p += (size_t)SREP * 768 * sizeof(float);
    float* goutR = (float*)p; p += (size_t)GREP * GSZ * sizeof(float);
    int* deg = (int*)p; p += (size_t)3 * N_NODES * 4;
    int* row_ptr = (int*)p; p += (size_t)3 * (N_NODES + 1) * 4;
    int* cur = (int*)p; p += (size_t)3 * N_NODES * 4;
    int* gcur = (int*)p; p += (size_t)3 * NCH2 * 4;
    int* edge_src = (int*)p; p += (size_t)3 * N_EDGES * 4;
    unsigned long long* chunkbuf = (unsigned long long*)p; p += (size_t)3 * N_EDGES * 8;

    hipMemsetAsync(statsR, 0, (size_t)SREP * 768 * 4, stream);
    hipMemsetAsync(goutR, 0, (size_t)GREP * GSZ * 4, stream);

    // CSR build: count -> scan(+chunk cursors) -> partition -> place -> sort
    hipMemsetAsync(deg, 0, (size_t)3 * N_NODES * 4, stream);
    dim3 eb((N_EDGES + 255) / 256, 3);
    count_deg_kernel<<<eb, 256, 0, stream>>>(dst, deg);
    scan_kernel<<<3, 1024, 0, stream>>>(deg, row_ptr, cur, gcur);
    partA_kernel<<<dim3(NSLA, 3), 256, 0, stream>>>(src, dst, gcur, chunkbuf);
    fillB_kernel<<<dim3(2 * NCH2, 3), 256, 0, stream>>>(row_ptr, chunkbuf, cur, edge_src);
    sort_adj_kernel<<<(3 * N_NODES + 255) / 256, 256, 0, stream>>>(row_ptr, edge_src);

    prep_init_kernel<<<217, 256, 0, stream>>>(W1_self, W1_neigh, Wbt1,
                                              emb_h, emb_p, emb_hp, emb_bf);

    dim3 gemm_grid((N_NODES + 127) / 128, 3);
    dim3 agg_grid((N_NODES + 95) / 96, 3);

    // ---- layer 1 (K = 64; nmean ld=64 in hpB via emb-table gather; out hpA) ----
    aggregate1_kernel<<<dim3((N_NODES + 31) / 32, 3), 256, 0, stream>>>(
        h_idx, p_idx, hp_idx, emb_bf, row_ptr, edge_src, hpB);
    gemm_kernel<64, true, true><<<gemm_grid, 512, 0, stream>>>(
        emb_bf /*unused*/, hpB, Wbt1, b1, a1, hpA, statsR, seg, goutR, 0,
        emb_bf, h_idx, p_idx, hp_idx);
    finalize_kernel<<<3, H, 0, stream>>>(statsR, gamma1, beta1, st_all);

    // ---- layers 2-4 (K = 128; out aliases nmean; last layer skips hp store) ----
    unsigned short* xin = hpA;
    unsigned short* xout = hpB;
    for (int l = 0; l < 3; l++) {
        const float* st_prev = st_all + (size_t)l * 3 * 2 * H;
        prep_kernel<<<387, 256, 0, stream>>>(
            W_self + (size_t)l * 3 * H * H, W_neigh + (size_t)l * 3 * H * H,
            b + (size_t)l * 3 * H, st_prev, Wbt, biasp);
        aggregate_kernel<true><<<agg_grid, 256, 0, stream>>>(
            xin, row_ptr, edge_src, st_prev, xout);
        if (l < 2)
            gemm_kernel<128, false, true><<<gemm_grid, 512, 0, stream>>>(
                xin, xout, Wbt, biasp, a + (size_t)l * 3 * H, xout, statsR, seg, goutR, l + 1,
                nullptr, nullptr, nullptr, nullptr);
        else
            gemm_kernel<128, false, false><<<gemm_grid, 512, 0, stream>>>(
                xin, xout, Wbt, biasp, a + (size_t)l * 3 * H, xout, statsR, seg, goutR, l + 1,
                nullptr, nullptr, nullptr, nullptr);
        finalize_kernel<<<3, H, 0, stream>>>(
            statsR, gamma + (size_t)l * 3 * H, beta + (size_t)l * 3 * H,
            st_all + (size_t)(l + 1) * 3 * 2 * H);
        unsigned short* t = xin; xin = xout; xout = t;
    }

    scale_out_kernel<<<(GSZ + 255) / 256, 256, 0, stream>>>(out, goutR, seg, st_all);
}

// Round 18
// 553.654 us; speedup vs baseline: 1.2969x; 1.0812x over previous
//
#include <hip/hip_runtime.h>

#define N_NODES 50000
#define N_EDGES 400000
#define N_GRAPHS 64
#define EMB 64
#define H 128
#define EPS 1e-5f

#define NCH2 49            // dst chunks of 1024 nodes
#define NSLA 48            // partition slices
#define SREP 16            // stats replicas
#define GREP 4             // gout replicas
#define GSZ (N_GRAPHS * 3 * 4 * H)
#define SCH 13             // scan chunks of 4096

typedef __attribute__((ext_vector_type(8))) short bf16x8;
typedef __attribute__((ext_vector_type(4))) float f32x4;

__device__ __forceinline__ unsigned short f2b(float f) {
    unsigned int u = __builtin_bit_cast(unsigned int, f);
    unsigned int r = (u + 0x7fff + ((u >> 16) & 1)) >> 16;  // RNE
    return (unsigned short)r;
}

// ---------------- CSR build ----------------

__global__ void count_deg_kernel(const int* __restrict__ dst, int* __restrict__ deg) {
    int rel = blockIdx.y;
    int e = blockIdx.x * 256 + threadIdx.x;
    if (e < N_EDGES) atomicAdd(&deg[rel * N_NODES + dst[rel * N_EDGES + e]], 1);
}

// parallel scan, stage 1: per-chunk (4096) exclusive prefix + chunk totals
__global__ void local_scan_kernel(const int* __restrict__ deg, int* __restrict__ row_ptr,
                                  int* __restrict__ ctot) {
    int rel = blockIdx.y, chunk = blockIdx.x;
    int base = chunk * 4096;
    const int* d = deg + rel * N_NODES;
    int* rp = row_ptr + rel * (N_NODES + 1);
    __shared__ int sm[1024];
    int i0 = base + (int)threadIdx.x * 4;
    int v[4];
    int s = 0;
#pragma unroll
    for (int k = 0; k < 4; k++) { v[k] = (i0 + k < N_NODES) ? d[i0 + k] : 0; s += v[k]; }
    sm[threadIdx.x] = s;
    __syncthreads();
    for (int off = 1; off < 1024; off <<= 1) {
        int t = (threadIdx.x >= off) ? sm[threadIdx.x - off] : 0;
        __syncthreads();
        sm[threadIdx.x] += t;
        __syncthreads();
    }
    int run = sm[threadIdx.x] - s;   // exclusive within chunk
#pragma unroll
    for (int k = 0; k < 4; k++) {
        if (i0 + k < N_NODES) rp[i0 + k] = run;
        run += v[k];
    }
    if (threadIdx.x == 1023) ctot[rel * SCH + chunk] = sm[1023];
}

// stage 2: scan the 13 chunk totals per rel (in place -> exclusive offsets)
__global__ void chunk_scan_kernel(int* __restrict__ ctot, int* __restrict__ row_ptr) {
    int rel = blockIdx.x;
    if (threadIdx.x == 0) {
        int run = 0;
        for (int c = 0; c < SCH; c++) { int t = ctot[rel * SCH + c]; ctot[rel * SCH + c] = run; run += t; }
        row_ptr[rel * (N_NODES + 1) + N_NODES] = run;
    }
}

// stage 3: add chunk offsets; write cur and per-1024-chunk cursors gcur
__global__ void fixup_kernel(int* __restrict__ row_ptr, const int* __restrict__ ctot,
                             int* __restrict__ cur, int* __restrict__ gcur) {
    int i = blockIdx.x * 256 + threadIdx.x;
    if (i >= 3 * N_NODES) return;
    int rel = i / N_NODES, n = i - rel * N_NODES;
    int val = row_ptr[rel * (N_NODES + 1) + n] + ctot[rel * SCH + (n >> 12)];
    row_ptr[rel * (N_NODES + 1) + n] = val;
    cur[rel * N_NODES + n] = val;
    if ((n & 1023) == 0) gcur[rel * NCH2 + (n >> 10)] = val;
}

// Phase A: partition edges into dst-chunk-major staging buffer (contiguous runs)
__global__ __launch_bounds__(256) void partA_kernel(
        const int* __restrict__ src, const int* __restrict__ dst,
        int* __restrict__ gcur, unsigned long long* __restrict__ chunkbuf) {
    int rel = blockIdx.y;
    const int* ds = dst + (size_t)rel * N_EDGES;
    const int* ss = src + (size_t)rel * N_EDGES;
    unsigned long long* cb = chunkbuf + (size_t)rel * N_EDGES;
    __shared__ int cnt[NCH2];
    __shared__ int lcur[NCH2];
    int tid = threadIdx.x;
    if (tid < NCH2) cnt[tid] = 0;
    __syncthreads();
    for (int e = blockIdx.x * 256 + tid; e < N_EDGES; e += NSLA * 256)
        atomicAdd(&cnt[ds[e] >> 10], 1);
    __syncthreads();
    if (tid < NCH2) lcur[tid] = atomicAdd(&gcur[rel * NCH2 + tid], cnt[tid]);
    __syncthreads();
    for (int e = blockIdx.x * 256 + tid; e < N_EDGES; e += NSLA * 256) {
        int dn = ds[e], sn = ss[e];
        int idx = atomicAdd(&lcur[dn >> 10], 1);
        cb[idx] = ((unsigned long long)(unsigned)sn << 32) | (unsigned)dn;
    }
}

// Phase B: each chunk's region placed by 2 blocks
__global__ __launch_bounds__(256) void fillB_kernel(
        const int* __restrict__ row_ptr, const unsigned long long* __restrict__ chunkbuf,
        int* __restrict__ cur, int* __restrict__ edge_src) {
    int rel = blockIdx.y;
    int c = blockIdx.x >> 1, half = blockIdx.x & 1;
    const int* rp = row_ptr + rel * (N_NODES + 1);
    int lo = rp[c << 10];
    int hiN = min((c + 1) << 10, N_NODES);
    int hi = rp[hiN];
    const unsigned long long* cb = chunkbuf + (size_t)rel * N_EDGES;
    int* cu = cur + rel * N_NODES;
    int* es = edge_src + (size_t)rel * N_EDGES;
    for (int i = lo + half + 2 * (int)threadIdx.x; i < hi; i += 2 * 256) {
        unsigned long long pr = cb[i];
        int dn = (int)(pr & 0xffffffffu);
        int sn = (int)(pr >> 32);
        int pos = atomicAdd(&cu[dn], 1);
        es[pos] = sn;
    }
}

// sort each node's adjacency list by src
__global__ void sort_adj_kernel(const int* __restrict__ row_ptr, int* __restrict__ edge_src) {
    int i = blockIdx.x * 256 + threadIdx.x;
    if (i >= 3 * N_NODES) return;
    int rel = i / N_NODES, n = i - rel * N_NODES;
    const int* rp = row_ptr + rel * (N_NODES + 1);
    int* es = edge_src + rel * N_EDGES;
    int s0 = rp[n], s1 = rp[n + 1];
    for (int a = s0 + 1; a < s1; a++) {
        int key = es[a];
        int b = a - 1;
        while (b >= s0 && es[b] > key) { es[b + 1] = es[b]; b--; }
        es[b + 1] = key;
    }
}

// ---------------- Fused init: layer-1 weights + bf16 emb tables ----------------

__global__ void prep_init_kernel(const float* __restrict__ W1self, const float* __restrict__ W1neigh,
                                 unsigned short* __restrict__ Wbt1,
                                 const float* __restrict__ emb_h, const float* __restrict__ emb_p,
                                 const float* __restrict__ emb_hp,
                                 unsigned short* __restrict__ emb_bf) {
    if (blockIdx.x < 192) {
        int idx = blockIdx.x * 256 + threadIdx.x;
        int rel = idx / (H * 128), rem = idx % (H * 128);
        int c = rem / 128, k = rem % 128;
        float v = (k < 64) ? W1self[((size_t)rel * 64 + k) * H + c]
                           : W1neigh[((size_t)rel * 64 + (k - 64)) * H + c];
        Wbt1[idx] = f2b(v);
    } else {
        int i = (blockIdx.x - 192) * 256 + threadIdx.x;
        if (i >= 3 * 257 * EMB / 8) return;
        int rel = i / (257 * EMB / 8), j = i % (257 * EMB / 8);
        const float* emb = rel == 0 ? emb_h : (rel == 1 ? emb_p : emb_hp);
        const float* e = emb + (size_t)j * 8;
        unsigned short o[8];
#pragma unroll
        for (int k = 0; k < 8; k++) o[k] = f2b(e[k]);
        *(uint4*)&emb_bf[(size_t)rel * 257 * EMB + (size_t)j * 8] = *(uint4*)o;
    }
}

// ---------------- Layer-1 aggregation via emb tables (cache-resident) ----------------

__global__ __launch_bounds__(256) void aggregate1_kernel(
        const int* __restrict__ h_idx, const int* __restrict__ p_idx,
        const int* __restrict__ hp_idx,
        const unsigned short* __restrict__ emb_bf,
        const int* __restrict__ row_ptr, const int* __restrict__ edge_src,
        unsigned short* __restrict__ nmean) {
    const int TPN = 8;
    int rel = blockIdx.y;
    int node = blockIdx.x * 32 + threadIdx.x / TPN;
    int c8 = (threadIdx.x % TPN) * 8;
    if (node >= N_NODES) return;
    const int* idxarr = rel == 0 ? h_idx : (rel == 1 ? p_idx : hp_idx);
    const unsigned short* emb = emb_bf + (size_t)rel * 257 * EMB;
    const int* rp = row_ptr + rel * (N_NODES + 1);
    const int* es = edge_src + rel * N_EDGES;
    int s0 = rp[node], s1 = rp[node + 1];
    float acc[8];
#pragma unroll
    for (int j = 0; j < 8; j++) acc[j] = 0.f;

#define ACCUM(V)                                                                      \
    {                                                                                 \
        unsigned int w[4] = {(V).x, (V).y, (V).z, (V).w};                             \
        _Pragma("unroll") for (int j = 0; j < 4; j++) {                               \
            acc[2 * j] += __builtin_bit_cast(float, w[j] << 16);                      \
            acc[2 * j + 1] += __builtin_bit_cast(float, w[j] & 0xffff0000u);          \
        }                                                                             \
    }

    int e = s0;
    for (; e + 4 <= s1; e += 4) {
        int i0 = idxarr[es[e]], i1 = idxarr[es[e + 1]];
        int i2 = idxarr[es[e + 2]], i3 = idxarr[es[e + 3]];
        uint4 v0 = *(const uint4*)&emb[(size_t)i0 * EMB + c8];
        uint4 v1 = *(const uint4*)&emb[(size_t)i1 * EMB + c8];
        uint4 v2 = *(const uint4*)&emb[(size_t)i2 * EMB + c8];
        uint4 v3 = *(const uint4*)&emb[(size_t)i3 * EMB + c8];
        ACCUM(v0) ACCUM(v1) ACCUM(v2) ACCUM(v3)
    }
    for (; e < s1; e++) {
        uint4 v0 = *(const uint4*)&emb[(size_t)idxarr[es[e]] * EMB + c8];
        ACCUM(v0)
    }
    int deg = s1 - s0;
    float inv = 1.f / (float)max(deg, 1);
    unsigned short o[8];
#pragma unroll
    for (int j = 0; j < 8; j++)
        o[j] = (deg > 0) ? f2b(acc[j] * inv) : (unsigned short)0;
    *(uint4*)&nmean[((size_t)rel * N_NODES + node) * EMB + c8] = *(uint4*)o;
}

// ---------------- Layers 2-4 aggregation ----------------

template <bool FOLD>
__global__ __launch_bounds__(256) void aggregate_kernel(
        const unsigned short* __restrict__ x,
        const int* __restrict__ row_ptr, const int* __restrict__ edge_src,
        const float* __restrict__ st,
        unsigned short* __restrict__ nmean) {
    const int TPN = 16;
    int rel = blockIdx.y;
    int c8 = (threadIdx.x % TPN) * 8;
    int nloc = threadIdx.x / TPN;
    const int* rp = row_ptr + rel * (N_NODES + 1);
    const int* es = edge_src + rel * N_EDGES;
    const unsigned short* xr = x + (size_t)rel * N_NODES * H;

    float sj[8], tj[8];
    if (FOLD) {
#pragma unroll
        for (int j = 0; j < 8; j++) {
            sj[j] = st[rel * 2 * H + c8 + j];
            tj[j] = st[rel * 2 * H + H + c8 + j];
        }
    }

#pragma unroll
    for (int batch = 0; batch < 6; batch++) {
        int node = blockIdx.x * 96 + batch * 16 + nloc;
        if (node >= N_NODES) continue;
        int s0 = rp[node], s1 = rp[node + 1];
        float acc[8];
#pragma unroll
        for (int j = 0; j < 8; j++) acc[j] = 0.f;
        int e = s0;
        for (; e + 4 <= s1; e += 4) {
            int i0 = es[e], i1 = es[e + 1], i2 = es[e + 2], i3 = es[e + 3];
            uint4 v0 = *(const uint4*)&xr[(size_t)i0 * H + c8];
            uint4 v1 = *(const uint4*)&xr[(size_t)i1 * H + c8];
            uint4 v2 = *(const uint4*)&xr[(size_t)i2 * H + c8];
            uint4 v3 = *(const uint4*)&xr[(size_t)i3 * H + c8];
            ACCUM(v0) ACCUM(v1) ACCUM(v2) ACCUM(v3)
        }
        for (; e < s1; e++) {
            uint4 v0 = *(const uint4*)&xr[(size_t)es[e] * H + c8];
            ACCUM(v0)
        }
        int deg = s1 - s0;
        float inv = 1.f / (float)max(deg, 1);
        unsigned short o[8];
#pragma unroll
        for (int j = 0; j < 8; j++) {
            float m = acc[j] * inv;
            if (FOLD) m = sj[j] * m + tj[j];
            o[j] = (deg > 0) ? f2b(m) : (unsigned short)0;
        }
        *(uint4*)&nmean[((size_t)rel * N_NODES + node) * H + c8] = *(uint4*)o;
    }
#undef ACCUM
}

// ---- MFMA GEMM (512 threads, 8 waves, LDS-staged; proven structure):
//      hp = PReLU([x|nmean]@Wbt^T + b); fp32 col stats (16-way striped);
//      per-graph readout fused (4-way striped); STORE=false skips hp write. ----

template <int KX, bool G1, bool STORE>
__global__ __launch_bounds__(512) void gemm_kernel(
        const unsigned short* __restrict__ x,
        const unsigned short* __restrict__ nmean,
        const unsigned short* __restrict__ Wbt,
        const float* __restrict__ bias,
        const float* __restrict__ alpha,
        unsigned short* __restrict__ out,
        float* __restrict__ statsR,               // [SREP][3][256]
        const int* __restrict__ seg_all,
        float* __restrict__ goutR,                // [GREP][GSZ]
        int layer,
        const unsigned short* __restrict__ embt,
        const int* __restrict__ h_idx, const int* __restrict__ p_idx,
        const int* __restrict__ hp_idx) {
    const int KTOT = 2 * KX;
    int rel = blockIdx.y;
    int row0 = blockIdx.x * 128;
    const unsigned short* xr = x + (size_t)rel * N_NODES * KX;
    const unsigned short* nm = nmean + (size_t)rel * N_NODES * KX;
    const unsigned short* W = Wbt + (size_t)rel * H * KTOT;
    unsigned short* o = out + (size_t)rel * N_NODES * H;
    float* stats = statsR + (size_t)(blockIdx.x & (SREP - 1)) * 768;
    float* gout = goutR + (size_t)(blockIdx.x & (GREP - 1)) * GSZ;

    __shared__ __align__(16) short At[128][40];
    __shared__ __align__(16) short Bt[128][40];

    int tid = threadIdx.x;
    int lane = tid & 63;
    int wave = tid >> 6;          // 0..7
    int wr = wave >> 2;           // 0..1 (row half)
    int wcq = wave & 3;           // 0..3 (32-col strip)
    int l15 = lane & 15;
    int koff = (lane >> 4) * 8;

    f32x4 acc[4][2];
#pragma unroll
    for (int m = 0; m < 4; m++)
#pragma unroll
        for (int n = 0; n < 2; n++) acc[m][n] = (f32x4){0.f, 0.f, 0.f, 0.f};

    int seg = tid & 3;
    int rloc = tid >> 2;          // 0..127 (one staged row per thread)

    int nid0 = 0;
    if (G1) {
        const int* idxarr = rel == 0 ? h_idx : (rel == 1 ? p_idx : hp_idx);
        if (row0 + rloc < N_NODES) nid0 = idxarr[row0 + rloc];
    }
    const unsigned short* et = G1 ? (embt + (size_t)rel * 257 * EMB) : nullptr;

    for (int kc = 0; kc < KTOT; kc += 32) {
        const bool selfh = kc < KX;
        const unsigned short* Asrc = selfh ? xr : nm;
        int kb = selfh ? kc : kc - KX;
        {
            int gr = row0 + rloc;
            uint4 v = make_uint4(0u, 0u, 0u, 0u);
            if (gr < N_NODES) {
                if (G1 && selfh) v = *(const uint4*)&et[(size_t)nid0 * EMB + kb + seg * 8];
                else             v = *(const uint4*)&Asrc[(size_t)gr * KX + kb + seg * 8];
            }
            *(uint4*)&At[rloc][seg * 8] = v;
            *(uint4*)&Bt[rloc][seg * 8] = *(const uint4*)&W[(size_t)rloc * KTOT + kc + seg * 8];
        }
        __syncthreads();
        bf16x8 a[4], b[2];
#pragma unroll
        for (int m = 0; m < 4; m++) a[m] = *(const bf16x8*)&At[wr * 64 + m * 16 + l15][koff];
#pragma unroll
        for (int n = 0; n < 2; n++) b[n] = *(const bf16x8*)&Bt[wcq * 32 + n * 16 + l15][koff];
#pragma unroll
        for (int m = 0; m < 4; m++)
#pragma unroll
            for (int n = 0; n < 2; n++)
                acc[m][n] = __builtin_amdgcn_mfma_f32_16x16x32_bf16(a[m], b[n], acc[m][n], 0, 0, 0);
        __syncthreads();
    }

    float bs[2], as_[2];
#pragma unroll
    for (int n = 0; n < 2; n++) {
        int col = wcq * 32 + n * 16 + l15;
        bs[n] = bias[rel * H + col];
        as_[n] = alpha[rel * H + col];
    }
    const int* sg = seg_all + rel * N_NODES;
    float csum[2] = {0.f, 0.f}, cssq[2] = {0.f, 0.f};
    int curg = -1;
    float run[2] = {0.f, 0.f};
    int rbase = row0 + wr * 64 + (lane >> 4) * 4;
#pragma unroll
    for (int m = 0; m < 4; m++) {
#pragma unroll
        for (int j = 0; j < 4; j++) {
            int r = rbase + m * 16 + j;
            if (r >= N_NODES) continue;
            int g = sg[r];
            if (g != curg) {
                if (curg >= 0) {
                    float* ob = gout + (size_t)curg * (3 * 4 * H) + rel * (4 * H) + layer * H + wcq * 32 + l15;
#pragma unroll
                    for (int n = 0; n < 2; n++) { atomicAdd(ob + n * 16, run[n]); run[n] = 0.f; }
                }
                curg = g;
            }
#pragma unroll
            for (int n = 0; n < 2; n++) {
                float v = acc[m][n][j] + bs[n];
                v = v > 0.f ? v : as_[n] * v;
                if (STORE) o[(size_t)r * H + wcq * 32 + n * 16 + l15] = f2b(v);
                csum[n] += v;
                cssq[n] += v * v;
                run[n] += v;
            }
        }
    }
    if (curg >= 0) {
        float* ob = gout + (size_t)curg * (3 * 4 * H) + rel * (4 * H) + layer * H + wcq * 32 + l15;
#pragma unroll
        for (int n = 0; n < 2; n++) atomicAdd(ob + n * 16, run[n]);
    }
    __syncthreads();
    float* smS = (float*)&At[0][0];   // 128 cols x 8 contributors = 4 KB
    float* smQ = (float*)&Bt[0][0];
    int contrib = wr * 4 + (lane >> 4);
#pragma unroll
    for (int n = 0; n < 2; n++) {
        int col = wcq * 32 + n * 16 + l15;
        smS[col * 8 + contrib] = csum[n];
        smQ[col * 8 + contrib] = cssq[n];
    }
    __syncthreads();
    if (tid < 128) {
        float s = 0.f, q = 0.f;
#pragma unroll
        for (int i = 0; i < 8; i++) { s += smS[tid * 8 + i]; q += smQ[tid * 8 + i]; }
        atomicAdd(&stats[rel * 256 + tid], s);
        atomicAdd(&stats[rel * 256 + 128 + tid], q);
    }
}

// ---------------- BN stats (sum 16 replicas) -> affine (s,t); zero replicas ----------------

__global__ void finalize_kernel(float* __restrict__ statsR,
                                const float* __restrict__ gamma, const float* __restrict__ beta,
                                float* __restrict__ st) {
    int rel = blockIdx.x, c = threadIdx.x;
    float sum = 0.f, ssq = 0.f;
#pragma unroll
    for (int k = 0; k < SREP; k++) {
        sum += statsR[(size_t)k * 768 + rel * 256 + c];
        ssq += statsR[(size_t)k * 768 + rel * 256 + 128 + c];
        statsR[(size_t)k * 768 + rel * 256 + c] = 0.f;
        statsR[(size_t)k * 768 + rel * 256 + 128 + c] = 0.f;
    }
    const float invN = 1.f / N_NODES;
    float mu = sum * invN;
    float var = ssq * invN - mu * mu;
    float s = gamma[rel * H + c] * rsqrtf(var + EPS);
    st[rel * 2 * H + c] = s;
    st[rel * 2 * H + H + c] = beta[rel * H + c] - mu * s;
}

// ---------------- Weight prep (layers 2-4) ----------------

__global__ void prep_kernel(const float* __restrict__ Wself, const float* __restrict__ Wneigh,
                            const float* __restrict__ b, const float* __restrict__ st,
                            unsigned short* __restrict__ Wbt, float* __restrict__ biasp) {
    if (blockIdx.x < 384) {
        int idx = blockIdx.x * 256 + threadIdx.x;
        int rel = idx / (H * 256), rem = idx % (H * 256);
        int c = rem / 256, k = rem % 256;
        float v;
        if (k < 128) v = st[rel * 2 * H + k] * Wself[((size_t)rel * H + k) * H + c];
        else         v = Wneigh[((size_t)rel * H + (k - 128)) * H + c];
        Wbt[idx] = f2b(v);
    } else if (threadIdx.x < H) {
        int rel = blockIdx.x - 384, c = threadIdx.x;
        const float* t = st + rel * 2 * H + H;
        float s = b[rel * H + c];
        for (int k = 0; k < H; k++) s += t[k] * Wself[((size_t)rel * H + k) * H + c];
        biasp[rel * H + c] = s;
    }
}

// ---------------- Final: sum gout replicas, mean + BN affine ----------------

__global__ void scale_out_kernel(float* __restrict__ out, const float* __restrict__ goutR,
                                 const int* __restrict__ seg,
                                 const float* __restrict__ st_all) {
    int i = blockIdx.x * 256 + threadIdx.x;
    if (i >= GSZ) return;
    int g = i / (3 * 4 * H), k = i % (3 * 4 * H);
    int rel = k / (4 * H), rem = k % (4 * H), layer = rem / H, c = rem % H;
    const int* sg = seg + rel * N_NODES;
    int lo = 0, hi = N_NODES;
    while (lo < hi) { int m = (lo + hi) >> 1; if (sg[m] < g) lo = m + 1; else hi = m; }
    int start = lo;
    hi = N_NODES;
    while (lo < hi) { int m = (lo + hi) >> 1; if (sg[m] <= g) lo = m + 1; else hi = m; }
    int cnt = lo - start;
    float sum = 0.f;
#pragma unroll
    for (int r = 0; r < GREP; r++) sum += goutR[(size_t)r * GSZ + i];
    float mean = sum / (float)max(cnt, 1);
    const float* st = st_all + ((size_t)layer * 3 + rel) * 2 * H;
    out[i] = st[c] * mean + st[H + c];
}

// ---------------- Orchestration ----------------

extern "C" void kernel_launch(void* const* d_in, const int* in_sizes, int n_in,
                              void* d_out, int out_size, void* d_ws, size_t ws_size,
                              hipStream_t stream) {
    const int* h_idx = (const int*)d_in[0];
    const int* p_idx = (const int*)d_in[1];
    const int* hp_idx = (const int*)d_in[2];
    const int* src = (const int*)d_in[3];
    const int* dst = (const int*)d_in[4];
    const int* seg = (const int*)d_in[5];
    const float* emb_h = (const float*)d_in[6];
    const float* emb_p = (const float*)d_in[7];
    const float* emb_hp = (const float*)d_in[8];
    const float* W1_self = (const float*)d_in[9];
    const float* W1_neigh = (const float*)d_in[10];
    const float* b1 = (const float*)d_in[11];
    const float* a1 = (const float*)d_in[12];
    const float* gamma1 = (const float*)d_in[13];
    const float* beta1 = (const float*)d_in[14];
    const float* W_self = (const float*)d_in[15];
    const float* W_neigh = (const float*)d_in[16];
    const float* b = (const float*)d_in[17];
    const float* a = (const float*)d_in[18];
    const float* gamma = (const float*)d_in[19];
    const float* beta = (const float*)d_in[20];
    float* out = (float*)d_out;

    // workspace
    char* p = (char*)d_ws;
    unsigned short* hpA = (unsigned short*)p; p += (size_t)3 * N_NODES * H * 2;
    unsigned short* hpB = (unsigned short*)p; p += (size_t)3 * N_NODES * H * 2;
    unsigned short* Wbt1 = (unsigned short*)p; p += (size_t)3 * H * 128 * 2;
    unsigned short* Wbt = (unsigned short*)p; p += (size_t)3 * H * 256 * 2;
    unsigned short* emb_bf = (unsigned short*)p; p += (size_t)3 * 257 * EMB * 2;
    float* biasp = (float*)p; p += 3 * H * sizeof(float);
    float* st_all = (float*)p; p += 4 * 3 * 2 * H * sizeof(float);
    float* statsR = (float*)p; p += (size_t)SREP * 768 * sizeof(float);
    float* goutR = (float*)p; p += (size_t)GREP * GSZ * sizeof(float);
    int* deg = (int*)p; p += (size_t)3 * N_NODES * 4;
    int* row_ptr = (int*)p; p += (size_t)3 * (N_NODES + 1) * 4;
    int* cur = (int*)p; p += (size_t)3 * N_NODES * 4;
    int* gcur = (int*)p; p += (size_t)3 * NCH2 * 4;
    int* ctot = (int*)p; p += (size_t)3 * SCH * 4;
    int* edge_src = (int*)p; p += (size_t)3 * N_EDGES * 4;
    unsigned long long* chunkbuf = (unsigned long long*)p; p += (size_t)3 * N_EDGES * 8;

    hipMemsetAsync(statsR, 0, (size_t)SREP * 768 * 4, stream);
    hipMemsetAsync(goutR, 0, (size_t)GREP * GSZ * 4, stream);

    // CSR build: count -> 3-stage parallel scan -> partition -> place -> sort
    hipMemsetAsync(deg, 0, (size_t)3 * N_NODES * 4, stream);
    dim3 eb((N_EDGES + 255) / 256, 3);
    count_deg_kernel<<<eb, 256, 0, stream>>>(dst, deg);
    local_scan_kernel<<<dim3(SCH, 3), 1024, 0, stream>>>(deg, row_ptr, ctot);
    chunk_scan_kernel<<<3, 32, 0, stream>>>(ctot, row_ptr);
    fixup_kernel<<<(3 * N_NODES + 255) / 256, 256, 0, stream>>>(row_ptr, ctot, cur, gcur);
    partA_kernel<<<dim3(NSLA, 3), 256, 0, stream>>>(src, dst, gcur, chunkbuf);
    fillB_kernel<<<dim3(2 * NCH2, 3), 256, 0, stream>>>(row_ptr, chunkbuf, cur, edge_src);
    sort_adj_kernel<<<(3 * N_NODES + 255) / 256, 256, 0, stream>>>(row_ptr, edge_src);

    prep_init_kernel<<<217, 256, 0, stream>>>(W1_self, W1_neigh, Wbt1,
                                              emb_h, emb_p, emb_hp, emb_bf);

    dim3 gemm_grid((N_NODES + 127) / 128, 3);
    dim3 agg_grid((N_NODES + 95) / 96, 3);

    // ---- layer 1 (K = 64; nmean ld=64 in hpB via emb-table gather; out hpA) ----
    aggregate1_kernel<<<dim3((N_NODES + 31) / 32, 3), 256, 0, stream>>>(
        h_idx, p_idx, hp_idx, emb_bf, row_ptr, edge_src, hpB);
    gemm_kernel<64, true, true><<<gemm_grid, 512, 0, stream>>>(
        emb_bf /*unused*/, hpB, Wbt1, b1, a1, hpA, statsR, seg, goutR, 0,
        emb_bf, h_idx, p_idx, hp_idx);
    finalize_kernel<<<3, H, 0, stream>>>(statsR, gamma1, beta1, st_all);

    // ---- layers 2-4 (K = 128; out aliases nmean; last layer skips hp store) ----
    unsigned short* xin = hpA;
    unsigned short* xout = hpB;
    for (int l = 0; l < 3; l++) {
        const float* st_prev = st_all + (size_t)l * 3 * 2 * H;
        prep_kernel<<<387, 256, 0, stream>>>(
            W_self + (size_t)l * 3 * H * H, W_neigh + (size_t)l * 3 * H * H,
            b + (size_t)l * 3 * H, st_prev, Wbt, biasp);
        aggregate_kernel<true><<<agg_grid, 256, 0, stream>>>(
            xin, row_ptr, edge_src, st_prev, xout);
        if (l < 2)
            gemm_kernel<128, false, true><<<gemm_grid, 512, 0, stream>>>(
                xin, xout, Wbt, biasp, a + (size_t)l * 3 * H, xout, statsR, seg, goutR, l + 1,
                nullptr, nullptr, nullptr, nullptr);
        else
            gemm_kernel<128, false, false><<<gemm_grid, 512, 0, stream>>>(
                xin, xout, Wbt, biasp, a + (size_t)l * 3 * H, xout, statsR, seg, goutR, l + 1,
                nullptr, nullptr, nullptr, nullptr);
        finalize_kernel<<<3, H, 0, stream>>>(
            statsR, gamma + (size_t)l * 3 * H, beta + (size_t)l * 3 * H,
            st_all + (size_t)(l + 1) * 3 * 2 * H);
        unsigned short* t = xin; xin = xout; xout = t;
    }

    scale_out_kernel<<<(GSZ + 255) / 256, 256, 0, stream>>>(out, goutR, seg, st_all);
}

// Round 19
// 544.115 us; speedup vs baseline: 1.3197x; 1.0175x over previous
//
#include <hip/hip_runtime.h>

#define N_NODES 50000
#define N_EDGES 400000
#define N_GRAPHS 64
#define EMB 64
#define H 128
#define EPS 1e-5f

#define NCH2 49            // dst chunks of 1024 nodes
#define NSLA 48            // partition slices
#define SREP 16            // stats replicas
#define GREP 4             // gout replicas
#define GSZ (N_GRAPHS * 3 * 4 * H)
#define SCH 13             // scan chunks of 4096

typedef __attribute__((ext_vector_type(8))) short bf16x8;
typedef __attribute__((ext_vector_type(4))) float f32x4;

__device__ __forceinline__ unsigned short f2b(float f) {
    unsigned int u = __builtin_bit_cast(unsigned int, f);
    unsigned int r = (u + 0x7fff + ((u >> 16) & 1)) >> 16;  // RNE
    return (unsigned short)r;
}

// ---------------- CSR build ----------------

__global__ void count_deg_kernel(const int* __restrict__ dst, int* __restrict__ deg) {
    int rel = blockIdx.y;
    int e = blockIdx.x * 256 + threadIdx.x;
    if (e < N_EDGES) atomicAdd(&deg[rel * N_NODES + dst[rel * N_EDGES + e]], 1);
}

// parallel scan, stage 1: per-chunk (4096) exclusive prefix + chunk totals
__global__ void local_scan_kernel(const int* __restrict__ deg, int* __restrict__ row_ptr,
                                  int* __restrict__ ctot) {
    int rel = blockIdx.y, chunk = blockIdx.x;
    int base = chunk * 4096;
    const int* d = deg + rel * N_NODES;
    int* rp = row_ptr + rel * (N_NODES + 1);
    __shared__ int sm[1024];
    int i0 = base + (int)threadIdx.x * 4;
    int v[4];
    int s = 0;
#pragma unroll
    for (int k = 0; k < 4; k++) { v[k] = (i0 + k < N_NODES) ? d[i0 + k] : 0; s += v[k]; }
    sm[threadIdx.x] = s;
    __syncthreads();
    for (int off = 1; off < 1024; off <<= 1) {
        int t = (threadIdx.x >= off) ? sm[threadIdx.x - off] : 0;
        __syncthreads();
        sm[threadIdx.x] += t;
        __syncthreads();
    }
    int run = sm[threadIdx.x] - s;   // exclusive within chunk
#pragma unroll
    for (int k = 0; k < 4; k++) {
        if (i0 + k < N_NODES) rp[i0 + k] = run;
        run += v[k];
    }
    if (threadIdx.x == 1023) ctot[rel * SCH + chunk] = sm[1023];
}

// stage 2: scan the 13 chunk totals per rel (in place -> exclusive offsets)
__global__ void chunk_scan_kernel(int* __restrict__ ctot, int* __restrict__ row_ptr) {
    int rel = blockIdx.x;
    if (threadIdx.x == 0) {
        int run = 0;
        for (int c = 0; c < SCH; c++) { int t = ctot[rel * SCH + c]; ctot[rel * SCH + c] = run; run += t; }
        row_ptr[rel * (N_NODES + 1) + N_NODES] = run;
    }
}

// stage 3: add chunk offsets; write cur and per-1024-chunk cursors gcur
__global__ void fixup_kernel(int* __restrict__ row_ptr, const int* __restrict__ ctot,
                             int* __restrict__ cur, int* __restrict__ gcur) {
    int i = blockIdx.x * 256 + threadIdx.x;
    if (i >= 3 * N_NODES) return;
    int rel = i / N_NODES, n = i - rel * N_NODES;
    int val = row_ptr[rel * (N_NODES + 1) + n] + ctot[rel * SCH + (n >> 12)];
    row_ptr[rel * (N_NODES + 1) + n] = val;
    cur[rel * N_NODES + n] = val;
    if ((n & 1023) == 0) gcur[rel * NCH2 + (n >> 10)] = val;
}

// Phase A: partition edges into dst-chunk-major staging buffer (contiguous runs)
__global__ __launch_bounds__(256) void partA_kernel(
        const int* __restrict__ src, const int* __restrict__ dst,
        int* __restrict__ gcur, unsigned long long* __restrict__ chunkbuf) {
    int rel = blockIdx.y;
    const int* ds = dst + (size_t)rel * N_EDGES;
    const int* ss = src + (size_t)rel * N_EDGES;
    unsigned long long* cb = chunkbuf + (size_t)rel * N_EDGES;
    __shared__ int cnt[NCH2];
    __shared__ int lcur[NCH2];
    int tid = threadIdx.x;
    if (tid < NCH2) cnt[tid] = 0;
    __syncthreads();
    for (int e = blockIdx.x * 256 + tid; e < N_EDGES; e += NSLA * 256)
        atomicAdd(&cnt[ds[e] >> 10], 1);
    __syncthreads();
    if (tid < NCH2) lcur[tid] = atomicAdd(&gcur[rel * NCH2 + tid], cnt[tid]);
    __syncthreads();
    for (int e = blockIdx.x * 256 + tid; e < N_EDGES; e += NSLA * 256) {
        int dn = ds[e], sn = ss[e];
        int idx = atomicAdd(&lcur[dn >> 10], 1);
        cb[idx] = ((unsigned long long)(unsigned)sn << 32) | (unsigned)dn;
    }
}

// Phase B: each chunk's region placed by 2 blocks
__global__ __launch_bounds__(256) void fillB_kernel(
        const int* __restrict__ row_ptr, const unsigned long long* __restrict__ chunkbuf,
        int* __restrict__ cur, int* __restrict__ edge_src) {
    int rel = blockIdx.y;
    int c = blockIdx.x >> 1, half = blockIdx.x & 1;
    const int* rp = row_ptr + rel * (N_NODES + 1);
    int lo = rp[c << 10];
    int hiN = min((c + 1) << 10, N_NODES);
    int hi = rp[hiN];
    const unsigned long long* cb = chunkbuf + (size_t)rel * N_EDGES;
    int* cu = cur + rel * N_NODES;
    int* es = edge_src + (size_t)rel * N_EDGES;
    for (int i = lo + half + 2 * (int)threadIdx.x; i < hi; i += 2 * 256) {
        unsigned long long pr = cb[i];
        int dn = (int)(pr & 0xffffffffu);
        int sn = (int)(pr >> 32);
        int pos = atomicAdd(&cu[dn], 1);
        es[pos] = sn;
    }
}

// sort each node's adjacency list by src
__global__ void sort_adj_kernel(const int* __restrict__ row_ptr, int* __restrict__ edge_src) {
    int i = blockIdx.x * 256 + threadIdx.x;
    if (i >= 3 * N_NODES) return;
    int rel = i / N_NODES, n = i - rel * N_NODES;
    const int* rp = row_ptr + rel * (N_NODES + 1);
    int* es = edge_src + rel * N_EDGES;
    int s0 = rp[n], s1 = rp[n + 1];
    for (int a = s0 + 1; a < s1; a++) {
        int key = es[a];
        int b = a - 1;
        while (b >= s0 && es[b] > key) { es[b + 1] = es[b]; b--; }
        es[b + 1] = key;
    }
}

// ---------------- Fused init: layer-1 weights + bf16 emb tables ----------------

__global__ void prep_init_kernel(const float* __restrict__ W1self, const float* __restrict__ W1neigh,
                                 unsigned short* __restrict__ Wbt1,
                                 const float* __restrict__ emb_h, const float* __restrict__ emb_p,
                                 const float* __restrict__ emb_hp,
                                 unsigned short* __restrict__ emb_bf) {
    if (blockIdx.x < 192) {
        int idx = blockIdx.x * 256 + threadIdx.x;
        int rel = idx / (H * 128), rem = idx % (H * 128);
        int c = rem / 128, k = rem % 128;
        float v = (k < 64) ? W1self[((size_t)rel * 64 + k) * H + c]
                           : W1neigh[((size_t)rel * 64 + (k - 64)) * H + c];
        Wbt1[idx] = f2b(v);
    } else {
        int i = (blockIdx.x - 192) * 256 + threadIdx.x;
        if (i >= 3 * 257 * EMB / 8) return;
        int rel = i / (257 * EMB / 8), j = i % (257 * EMB / 8);
        const float* emb = rel == 0 ? emb_h : (rel == 1 ? emb_p : emb_hp);
        const float* e = emb + (size_t)j * 8;
        unsigned short o[8];
#pragma unroll
        for (int k = 0; k < 8; k++) o[k] = f2b(e[k]);
        *(uint4*)&emb_bf[(size_t)rel * 257 * EMB + (size_t)j * 8] = *(uint4*)o;
    }
}

// ---------------- Layer-1 aggregation via emb tables (cache-resident) ----------------

__global__ __launch_bounds__(256) void aggregate1_kernel(
        const int* __restrict__ h_idx, const int* __restrict__ p_idx,
        const int* __restrict__ hp_idx,
        const unsigned short* __restrict__ emb_bf,
        const int* __restrict__ row_ptr, const int* __restrict__ edge_src,
        unsigned short* __restrict__ nmean) {
    const int TPN = 8;
    int rel = blockIdx.y;
    int node = blockIdx.x * 32 + threadIdx.x / TPN;
    int c8 = (threadIdx.x % TPN) * 8;
    if (node >= N_NODES) return;
    const int* idxarr = rel == 0 ? h_idx : (rel == 1 ? p_idx : hp_idx);
    const unsigned short* emb = emb_bf + (size_t)rel * 257 * EMB;
    const int* rp = row_ptr + rel * (N_NODES + 1);
    const int* es = edge_src + rel * N_EDGES;
    int s0 = rp[node], s1 = rp[node + 1];
    float acc[8];
#pragma unroll
    for (int j = 0; j < 8; j++) acc[j] = 0.f;

#define ACCUM(V)                                                                      \
    {                                                                                 \
        unsigned int w[4] = {(V).x, (V).y, (V).z, (V).w};                             \
        _Pragma("unroll") for (int j = 0; j < 4; j++) {                               \
            acc[2 * j] += __builtin_bit_cast(float, w[j] << 16);                      \
            acc[2 * j + 1] += __builtin_bit_cast(float, w[j] & 0xffff0000u);          \
        }                                                                             \
    }

    int e = s0;
    for (; e + 4 <= s1; e += 4) {
        int i0 = idxarr[es[e]], i1 = idxarr[es[e + 1]];
        int i2 = idxarr[es[e + 2]], i3 = idxarr[es[e + 3]];
        uint4 v0 = *(const uint4*)&emb[(size_t)i0 * EMB + c8];
        uint4 v1 = *(const uint4*)&emb[(size_t)i1 * EMB + c8];
        uint4 v2 = *(const uint4*)&emb[(size_t)i2 * EMB + c8];
        uint4 v3 = *(const uint4*)&emb[(size_t)i3 * EMB + c8];
        ACCUM(v0) ACCUM(v1) ACCUM(v2) ACCUM(v3)
    }
    for (; e < s1; e++) {
        uint4 v0 = *(const uint4*)&emb[(size_t)idxarr[es[e]] * EMB + c8];
        ACCUM(v0)
    }
    int deg = s1 - s0;
    float inv = 1.f / (float)max(deg, 1);
    unsigned short o[8];
#pragma unroll
    for (int j = 0; j < 8; j++)
        o[j] = (deg > 0) ? f2b(acc[j] * inv) : (unsigned short)0;
    *(uint4*)&nmean[((size_t)rel * N_NODES + node) * EMB + c8] = *(uint4*)o;
}

// ---------------- Layers 2-4 aggregation ----------------

template <bool FOLD>
__global__ __launch_bounds__(256) void aggregate_kernel(
        const unsigned short* __restrict__ x,
        const int* __restrict__ row_ptr, const int* __restrict__ edge_src,
        const float* __restrict__ st,
        unsigned short* __restrict__ nmean) {
    const int TPN = 16;
    int rel = blockIdx.y;
    int c8 = (threadIdx.x % TPN) * 8;
    int nloc = threadIdx.x / TPN;
    const int* rp = row_ptr + rel * (N_NODES + 1);
    const int* es = edge_src + rel * N_EDGES;
    const unsigned short* xr = x + (size_t)rel * N_NODES * H;

    float sj[8], tj[8];
    if (FOLD) {
#pragma unroll
        for (int j = 0; j < 8; j++) {
            sj[j] = st[rel * 2 * H + c8 + j];
            tj[j] = st[rel * 2 * H + H + c8 + j];
        }
    }

#pragma unroll
    for (int batch = 0; batch < 6; batch++) {
        int node = blockIdx.x * 96 + batch * 16 + nloc;
        if (node >= N_NODES) continue;
        int s0 = rp[node], s1 = rp[node + 1];
        float acc[8];
#pragma unroll
        for (int j = 0; j < 8; j++) acc[j] = 0.f;
        int e = s0;
        for (; e + 4 <= s1; e += 4) {
            int i0 = es[e], i1 = es[e + 1], i2 = es[e + 2], i3 = es[e + 3];
            uint4 v0 = *(const uint4*)&xr[(size_t)i0 * H + c8];
            uint4 v1 = *(const uint4*)&xr[(size_t)i1 * H + c8];
            uint4 v2 = *(const uint4*)&xr[(size_t)i2 * H + c8];
            uint4 v3 = *(const uint4*)&xr[(size_t)i3 * H + c8];
            ACCUM(v0) ACCUM(v1) ACCUM(v2) ACCUM(v3)
        }
        for (; e < s1; e++) {
            uint4 v0 = *(const uint4*)&xr[(size_t)es[e] * H + c8];
            ACCUM(v0)
        }
        int deg = s1 - s0;
        float inv = 1.f / (float)max(deg, 1);
        unsigned short o[8];
#pragma unroll
        for (int j = 0; j < 8; j++) {
            float m = acc[j] * inv;
            if (FOLD) m = sj[j] * m + tj[j];
            o[j] = (deg > 0) ? f2b(m) : (unsigned short)0;
        }
        *(uint4*)&nmean[((size_t)rel * N_NODES + node) * H + c8] = *(uint4*)o;
    }
#undef ACCUM
}

// ---- MFMA GEMM (512 threads, 8 waves, LDS-staged, BK=64 chunks):
//      hp = PReLU([x|nmean]@Wbt^T + b); fp32 col stats (16-way striped);
//      per-graph readout fused (4-way striped); STORE=false skips hp write. ----

template <int KX, bool G1, bool STORE>
__global__ __launch_bounds__(512) void gemm_kernel(
        const unsigned short* __restrict__ x,
        const unsigned short* __restrict__ nmean,
        const unsigned short* __restrict__ Wbt,
        const float* __restrict__ bias,
        const float* __restrict__ alpha,
        unsigned short* __restrict__ out,
        float* __restrict__ statsR,               // [SREP][3][256]
        const int* __restrict__ seg_all,
        float* __restrict__ goutR,                // [GREP][GSZ]
        int layer,
        const unsigned short* __restrict__ embt,
        const int* __restrict__ h_idx, const int* __restrict__ p_idx,
        const int* __restrict__ hp_idx) {
    const int KTOT = 2 * KX;
    const int NCH = KTOT / 64;                    // 64-wide K chunks
    int rel = blockIdx.y;
    int row0 = blockIdx.x * 128;
    const unsigned short* xr = x + (size_t)rel * N_NODES * KX;
    const unsigned short* nm = nmean + (size_t)rel * N_NODES * KX;
    const unsigned short* W = Wbt + (size_t)rel * H * KTOT;
    unsigned short* o = out + (size_t)rel * N_NODES * H;
    float* stats = statsR + (size_t)(blockIdx.x & (SREP - 1)) * 768;
    float* gout = goutR + (size_t)(blockIdx.x & (GREP - 1)) * GSZ;

    __shared__ __align__(16) short At[128][72];
    __shared__ __align__(16) short Bt[128][72];

    int tid = threadIdx.x;
    int lane = tid & 63;
    int wave = tid >> 6;          // 0..7
    int wr = wave >> 2;           // 0..1 (row half)
    int wcq = wave & 3;           // 0..3 (32-col strip)
    int l15 = lane & 15;
    int koff = (lane >> 4) * 8;

    f32x4 acc[4][2];
#pragma unroll
    for (int m = 0; m < 4; m++)
#pragma unroll
        for (int n = 0; n < 2; n++) acc[m][n] = (f32x4){0.f, 0.f, 0.f, 0.f};

    int seg = tid & 3;
    int rloc = tid >> 2;          // 0..127 (one staged row per thread)

    int nid0 = 0;
    if (G1) {
        const int* idxarr = rel == 0 ? h_idx : (rel == 1 ? p_idx : hp_idx);
        if (row0 + rloc < N_NODES) nid0 = idxarr[row0 + rloc];
    }
    const unsigned short* et = G1 ? (embt + (size_t)rel * 257 * EMB) : nullptr;

    for (int ch = 0; ch < NCH; ch++) {
        int kc = ch * 64;
        const bool selfh = kc < KX;
        const unsigned short* Asrc = selfh ? xr : nm;
        int kb = selfh ? kc : kc - KX;
        {
            int gr = row0 + rloc;
            uint4 v0 = make_uint4(0u, 0u, 0u, 0u), v1 = v0;
            if (gr < N_NODES) {
                if (G1 && selfh) {
                    v0 = *(const uint4*)&et[(size_t)nid0 * EMB + kb + seg * 8];
                    v1 = *(const uint4*)&et[(size_t)nid0 * EMB + kb + 32 + seg * 8];
                } else {
                    v0 = *(const uint4*)&Asrc[(size_t)gr * KX + kb + seg * 8];
                    v1 = *(const uint4*)&Asrc[(size_t)gr * KX + kb + 32 + seg * 8];
                }
            }
            *(uint4*)&At[rloc][seg * 8] = v0;
            *(uint4*)&At[rloc][32 + seg * 8] = v1;
            *(uint4*)&Bt[rloc][seg * 8] = *(const uint4*)&W[(size_t)rloc * KTOT + kc + seg * 8];
            *(uint4*)&Bt[rloc][32 + seg * 8] = *(const uint4*)&W[(size_t)rloc * KTOT + kc + 32 + seg * 8];
        }
        __syncthreads();
#pragma unroll
        for (int kk = 0; kk < 64; kk += 32) {
            bf16x8 a[4], b[2];
#pragma unroll
            for (int m = 0; m < 4; m++) a[m] = *(const bf16x8*)&At[wr * 64 + m * 16 + l15][kk + koff];
#pragma unroll
            for (int n = 0; n < 2; n++) b[n] = *(const bf16x8*)&Bt[wcq * 32 + n * 16 + l15][kk + koff];
#pragma unroll
            for (int m = 0; m < 4; m++)
#pragma unroll
                for (int n = 0; n < 2; n++)
                    acc[m][n] = __builtin_amdgcn_mfma_f32_16x16x32_bf16(a[m], b[n], acc[m][n], 0, 0, 0);
        }
        __syncthreads();
    }

    float bs[2], as_[2];
#pragma unroll
    for (int n = 0; n < 2; n++) {
        int col = wcq * 32 + n * 16 + l15;
        bs[n] = bias[rel * H + col];
        as_[n] = alpha[rel * H + col];
    }
    const int* sg = seg_all + rel * N_NODES;
    float csum[2] = {0.f, 0.f}, cssq[2] = {0.f, 0.f};
    int curg = -1;
    float run[2] = {0.f, 0.f};
    int rbase = row0 + wr * 64 + (lane >> 4) * 4;
#pragma unroll
    for (int m = 0; m < 4; m++) {
#pragma unroll
        for (int j = 0; j < 4; j++) {
            int r = rbase + m * 16 + j;
            if (r >= N_NODES) continue;
            int g = sg[r];
            if (g != curg) {
                if (curg >= 0) {
                    float* ob = gout + (size_t)curg * (3 * 4 * H) + rel * (4 * H) + layer * H + wcq * 32 + l15;
#pragma unroll
                    for (int n = 0; n < 2; n++) { atomicAdd(ob + n * 16, run[n]); run[n] = 0.f; }
                }
                curg = g;
            }
#pragma unroll
            for (int n = 0; n < 2; n++) {
                float v = acc[m][n][j] + bs[n];
                v = v > 0.f ? v : as_[n] * v;
                if (STORE) o[(size_t)r * H + wcq * 32 + n * 16 + l15] = f2b(v);
                csum[n] += v;
                cssq[n] += v * v;
                run[n] += v;
            }
        }
    }
    if (curg >= 0) {
        float* ob = gout + (size_t)curg * (3 * 4 * H) + rel * (4 * H) + layer * H + wcq * 32 + l15;
#pragma unroll
        for (int n = 0; n < 2; n++) atomicAdd(ob + n * 16, run[n]);
    }
    __syncthreads();
    float* smS = (float*)&At[0][0];   // 128 cols x 8 contributors = 4 KB
    float* smQ = (float*)&Bt[0][0];
    int contrib = wr * 4 + (lane >> 4);
#pragma unroll
    for (int n = 0; n < 2; n++) {
        int col = wcq * 32 + n * 16 + l15;
        smS[col * 8 + contrib] = csum[n];
        smQ[col * 8 + contrib] = cssq[n];
    }
    __syncthreads();
    if (tid < 128) {
        float s = 0.f, q = 0.f;
#pragma unroll
        for (int i = 0; i < 8; i++) { s += smS[tid * 8 + i]; q += smQ[tid * 8 + i]; }
        atomicAdd(&stats[rel * 256 + tid], s);
        atomicAdd(&stats[rel * 256 + 128 + tid], q);
    }
}

// ---------------- BN stats (sum 16 replicas) -> affine (s,t); zero replicas ----------------

__global__ void finalize_kernel(float* __restrict__ statsR,
                                const float* __restrict__ gamma, const float* __restrict__ beta,
                                float* __restrict__ st) {
    int rel = blockIdx.x, c = threadIdx.x;
    float sum = 0.f, ssq = 0.f;
#pragma unroll
    for (int k = 0; k < SREP; k++) {
        sum += statsR[(size_t)k * 768 + rel * 256 + c];
        ssq += statsR[(size_t)k * 768 + rel * 256 + 128 + c];
        statsR[(size_t)k * 768 + rel * 256 + c] = 0.f;
        statsR[(size_t)k * 768 + rel * 256 + 128 + c] = 0.f;
    }
    const float invN = 1.f / N_NODES;
    float mu = sum * invN;
    float var = ssq * invN - mu * mu;
    float s = gamma[rel * H + c] * rsqrtf(var + EPS);
    st[rel * 2 * H + c] = s;
    st[rel * 2 * H + H + c] = beta[rel * H + c] - mu * s;
}

// ---------------- Weight prep (layers 2-4) ----------------

__global__ void prep_kernel(const float* __restrict__ Wself, const float* __restrict__ Wneigh,
                            const float* __restrict__ b, const float* __restrict__ st,
                            unsigned short* __restrict__ Wbt, float* __restrict__ biasp) {
    if (blockIdx.x < 384) {
        int idx = blockIdx.x * 256 + threadIdx.x;
        int rel = idx / (H * 256), rem = idx % (H * 256);
        int c = rem / 256, k = rem % 256;
        float v;
        if (k < 128) v = st[rel * 2 * H + k] * Wself[((size_t)rel * H + k) * H + c];
        else         v = Wneigh[((size_t)rel * H + (k - 128)) * H + c];
        Wbt[idx] = f2b(v);
    } else if (threadIdx.x < H) {
        int rel = blockIdx.x - 384, c = threadIdx.x;
        const float* t = st + rel * 2 * H + H;
        float s = b[rel * H + c];
        for (int k = 0; k < H; k++) s += t[k] * Wself[((size_t)rel * H + k) * H + c];
        biasp[rel * H + c] = s;
    }
}

// ---------------- Final: sum gout replicas, mean + BN affine ----------------

__global__ void scale_out_kernel(float* __restrict__ out, const float* __restrict__ goutR,
                                 const int* __restrict__ seg,
                                 const float* __restrict__ st_all) {
    int i = blockIdx.x * 256 + threadIdx.x;
    if (i >= GSZ) return;
    int g = i / (3 * 4 * H), k = i % (3 * 4 * H);
    int rel = k / (4 * H), rem = k % (4 * H), layer = rem / H, c = rem % H;
    const int* sg = seg + rel * N_NODES;
    int lo = 0, hi = N_NODES;
    while (lo < hi) { int m = (lo + hi) >> 1; if (sg[m] < g) lo = m + 1; else hi = m; }
    int start = lo;
    hi = N_NODES;
    while (lo < hi) { int m = (lo + hi) >> 1; if (sg[m] <= g) lo = m + 1; else hi = m; }
    int cnt = lo - start;
    float sum = 0.f;
#pragma unroll
    for (int r = 0; r < GREP; r++) sum += goutR[(size_t)r * GSZ + i];
    float mean = sum / (float)max(cnt, 1);
    const float* st = st_all + ((size_t)layer * 3 + rel) * 2 * H;
    out[i] = st[c] * mean + st[H + c];
}

// ---------------- Orchestration ----------------

extern "C" void kernel_launch(void* const* d_in, const int* in_sizes, int n_in,
                              void* d_out, int out_size, void* d_ws, size_t ws_size,
                              hipStream_t stream) {
    const int* h_idx = (const int*)d_in[0];
    const int* p_idx = (const int*)d_in[1];
    const int* hp_idx = (const int*)d_in[2];
    const int* src = (const int*)d_in[3];
    const int* dst = (const int*)d_in[4];
    const int* seg = (const int*)d_in[5];
    const float* emb_h = (const float*)d_in[6];
    const float* emb_p = (const float*)d_in[7];
    const float* emb_hp = (const float*)d_in[8];
    const float* W1_self = (const float*)d_in[9];
    const float* W1_neigh = (const float*)d_in[10];
    const float* b1 = (const float*)d_in[11];
    const float* a1 = (const float*)d_in[12];
    const float* gamma1 = (const float*)d_in[13];
    const float* beta1 = (const float*)d_in[14];
    const float* W_self = (const float*)d_in[15];
    const float* W_neigh = (const float*)d_in[16];
    const float* b = (const float*)d_in[17];
    const float* a = (const float*)d_in[18];
    const float* gamma = (const float*)d_in[19];
    const float* beta = (const float*)d_in[20];
    float* out = (float*)d_out;

    // workspace
    char* p = (char*)d_ws;
    unsigned short* hpA = (unsigned short*)p; p += (size_t)3 * N_NODES * H * 2;
    unsigned short* hpB = (unsigned short*)p; p += (size_t)3 * N_NODES * H * 2;
    unsigned short* Wbt1 = (unsigned short*)p; p += (size_t)3 * H * 128 * 2;
    unsigned short* Wbt = (unsigned short*)p; p += (size_t)3 * H * 256 * 2;
    unsigned short* emb_bf = (unsigned short*)p; p += (size_t)3 * 257 * EMB * 2;
    float* biasp = (float*)p; p += 3 * H * sizeof(float);
    float* st_all = (float*)p; p += 4 * 3 * 2 * H * sizeof(float);
    float* statsR = (float*)p; p += (size_t)SREP * 768 * sizeof(float);
    float* goutR = (float*)p; p += (size_t)GREP * GSZ * sizeof(float);
    int* deg = (int*)p; p += (size_t)3 * N_NODES * 4;
    int* row_ptr = (int*)p; p += (size_t)3 * (N_NODES + 1) * 4;
    int* cur = (int*)p; p += (size_t)3 * N_NODES * 4;
    int* gcur = (int*)p; p += (size_t)3 * NCH2 * 4;
    int* ctot = (int*)p; p += (size_t)3 * SCH * 4;
    int* edge_src = (int*)p; p += (size_t)3 * N_EDGES * 4;
    unsigned long long* chunkbuf = (unsigned long long*)p; p += (size_t)3 * N_EDGES * 8;

    hipMemsetAsync(statsR, 0, (size_t)SREP * 768 * 4, stream);
    hipMemsetAsync(goutR, 0, (size_t)GREP * GSZ * 4, stream);

    // CSR build: count -> 3-stage parallel scan -> partition -> place -> sort
    hipMemsetAsync(deg, 0, (size_t)3 * N_NODES * 4, stream);
    dim3 eb((N_EDGES + 255) / 256, 3);
    count_deg_kernel<<<eb, 256, 0, stream>>>(dst, deg);
    local_scan_kernel<<<dim3(SCH, 3), 1024, 0, stream>>>(deg, row_ptr, ctot);
    chunk_scan_kernel<<<3, 32, 0, stream>>>(ctot, row_ptr);
    fixup_kernel<<<(3 * N_NODES + 255) / 256, 256, 0, stream>>>(row_ptr, ctot, cur, gcur);
    partA_kernel<<<dim3(NSLA, 3), 256, 0, stream>>>(src, dst, gcur, chunkbuf);
    fillB_kernel<<<dim3(2 * NCH2, 3), 256, 0, stream>>>(row_ptr, chunkbuf, cur, edge_src);
    sort_adj_kernel<<<(3 * N_NODES + 255) / 256, 256, 0, stream>>>(row_ptr, edge_src);

    prep_init_kernel<<<217, 256, 0, stream>>>(W1_self, W1_neigh, Wbt1,
                                              emb_h, emb_p, emb_hp, emb_bf);

    dim3 gemm_grid((N_NODES + 127) / 128, 3);
    dim3 agg_grid((N_NODES + 95) / 96, 3);

    // ---- layer 1 (K = 64; nmean ld=64 in hpB via emb-table gather; out hpA) ----
    aggregate1_kernel<<<dim3((N_NODES + 31) / 32, 3), 256, 0, stream>>>(
        h_idx, p_idx, hp_idx, emb_bf, row_ptr, edge_src, hpB);
    gemm_kernel<64, true, true><<<gemm_grid, 512, 0, stream>>>(
        emb_bf /*unused*/, hpB, Wbt1, b1, a1, hpA, statsR, seg, goutR, 0,
        emb_bf, h_idx, p_idx, hp_idx);
    finalize_kernel<<<3, H, 0, stream>>>(statsR, gamma1, beta1, st_all);

    // ---- layers 2-4 (K = 128; out aliases nmean; last layer skips hp store) ----
    unsigned short* xin = hpA;
    unsigned short* xout = hpB;
    for (int l = 0; l < 3; l++) {
        const float* st_prev = st_all + (size_t)l * 3 * 2 * H;
        prep_kernel<<<387, 256, 0, stream>>>(
            W_self + (size_t)l * 3 * H * H, W_neigh + (size_t)l * 3 * H * H,
            b + (size_t)l * 3 * H, st_prev, Wbt, biasp);
        aggregate_kernel<true><<<agg_grid, 256, 0, stream>>>(
            xin, row_ptr, edge_src, st_prev, xout);
        if (l < 2)
            gemm_kernel<128, false, true><<<gemm_grid, 512, 0, stream>>>(
                xin, xout, Wbt, biasp, a + (size_t)l * 3 * H, xout, statsR, seg, goutR, l + 1,
                nullptr, nullptr, nullptr, nullptr);
        else
            gemm_kernel<128, false, false><<<gemm_grid, 512, 0, stream>>>(
                xin, xout, Wbt, biasp, a + (size_t)l * 3 * H, xout, statsR, seg, goutR, l + 1,
                nullptr, nullptr, nullptr, nullptr);
        finalize_kernel<<<3, H, 0, stream>>>(
            statsR, gamma + (size_t)l * 3 * H, beta + (size_t)l * 3 * H,
            st_all + (size_t)(l + 1) * 3 * 2 * H);
        unsigned short* t = xin; xin = xout; xout = t;
    }

    scale_out_kernel<<<(GSZ + 255) / 256, 256, 0, stream>>>(out, goutR, seg, st_all);
}

// Round 20
// 538.097 us; speedup vs baseline: 1.3344x; 1.0112x over previous
//
#include <hip/hip_runtime.h>

#define N_NODES 50000
#define N_EDGES 400000
#define N_GRAPHS 64
#define EMB 64
#define H 128
#define EPS 1e-5f

#define NCH2 49            // dst chunks of 1024 nodes
#define NSLA 48            // partition slices
#define SREP 16            // stats replicas
#define GREP 4             // gout replicas
#define GSZ (N_GRAPHS * 3 * 4 * H)
#define SCH 13             // scan chunks of 4096

typedef __attribute__((ext_vector_type(8))) short bf16x8;
typedef __attribute__((ext_vector_type(4))) float f32x4;

__device__ __forceinline__ unsigned short f2b(float f) {
    unsigned int u = __builtin_bit_cast(unsigned int, f);
    unsigned int r = (u + 0x7fff + ((u >> 16) & 1)) >> 16;  // RNE
    return (unsigned short)r;
}

// ---------------- CSR build ----------------

__global__ void count_deg_kernel(const int* __restrict__ dst, int* __restrict__ deg) {
    int rel = blockIdx.y;
    int e = blockIdx.x * 256 + threadIdx.x;
    if (e < N_EDGES) atomicAdd(&deg[rel * N_NODES + dst[rel * N_EDGES + e]], 1);
}

// parallel scan, stage 1: per-chunk (4096) exclusive prefix + chunk totals
__global__ void local_scan_kernel(const int* __restrict__ deg, int* __restrict__ row_ptr,
                                  int* __restrict__ ctot) {
    int rel = blockIdx.y, chunk = blockIdx.x;
    int base = chunk * 4096;
    const int* d = deg + rel * N_NODES;
    int* rp = row_ptr + rel * (N_NODES + 1);
    __shared__ int sm[1024];
    int i0 = base + (int)threadIdx.x * 4;
    int v[4];
    int s = 0;
#pragma unroll
    for (int k = 0; k < 4; k++) { v[k] = (i0 + k < N_NODES) ? d[i0 + k] : 0; s += v[k]; }
    sm[threadIdx.x] = s;
    __syncthreads();
    for (int off = 1; off < 1024; off <<= 1) {
        int t = (threadIdx.x >= off) ? sm[threadIdx.x - off] : 0;
        __syncthreads();
        sm[threadIdx.x] += t;
        __syncthreads();
    }
    int run = sm[threadIdx.x] - s;   // exclusive within chunk
#pragma unroll
    for (int k = 0; k < 4; k++) {
        if (i0 + k < N_NODES) rp[i0 + k] = run;
        run += v[k];
    }
    if (threadIdx.x == 1023) ctot[rel * SCH + chunk] = sm[1023];
}

// stage 2: scan the 13 chunk totals per rel (in place -> exclusive offsets)
__global__ void chunk_scan_kernel(int* __restrict__ ctot, int* __restrict__ row_ptr) {
    int rel = blockIdx.x;
    if (threadIdx.x == 0) {
        int run = 0;
        for (int c = 0; c < SCH; c++) { int t = ctot[rel * SCH + c]; ctot[rel * SCH + c] = run; run += t; }
        row_ptr[rel * (N_NODES + 1) + N_NODES] = run;
    }
}

// stage 3: add chunk offsets; write cur and per-1024-chunk cursors gcur
__global__ void fixup_kernel(int* __restrict__ row_ptr, const int* __restrict__ ctot,
                             int* __restrict__ cur, int* __restrict__ gcur) {
    int i = blockIdx.x * 256 + threadIdx.x;
    if (i >= 3 * N_NODES) return;
    int rel = i / N_NODES, n = i - rel * N_NODES;
    int val = row_ptr[rel * (N_NODES + 1) + n] + ctot[rel * SCH + (n >> 12)];
    row_ptr[rel * (N_NODES + 1) + n] = val;
    cur[rel * N_NODES + n] = val;
    if ((n & 1023) == 0) gcur[rel * NCH2 + (n >> 10)] = val;
}

// Phase A: partition edges into dst-chunk-major staging buffer (contiguous runs)
__global__ __launch_bounds__(256) void partA_kernel(
        const int* __restrict__ src, const int* __restrict__ dst,
        int* __restrict__ gcur, unsigned long long* __restrict__ chunkbuf) {
    int rel = blockIdx.y;
    const int* ds = dst + (size_t)rel * N_EDGES;
    const int* ss = src + (size_t)rel * N_EDGES;
    unsigned long long* cb = chunkbuf + (size_t)rel * N_EDGES;
    __shared__ int cnt[NCH2];
    __shared__ int lcur[NCH2];
    int tid = threadIdx.x;
    if (tid < NCH2) cnt[tid] = 0;
    __syncthreads();
    for (int e = blockIdx.x * 256 + tid; e < N_EDGES; e += NSLA * 256)
        atomicAdd(&cnt[ds[e] >> 10], 1);
    __syncthreads();
    if (tid < NCH2) lcur[tid] = atomicAdd(&gcur[rel * NCH2 + tid], cnt[tid]);
    __syncthreads();
    for (int e = blockIdx.x * 256 + tid; e < N_EDGES; e += NSLA * 256) {
        int dn = ds[e], sn = ss[e];
        int idx = atomicAdd(&lcur[dn >> 10], 1);
        cb[idx] = ((unsigned long long)(unsigned)sn << 32) | (unsigned)dn;
    }
}

// Phase B: each chunk's region placed by 2 blocks
__global__ __launch_bounds__(256) void fillB_kernel(
        const int* __restrict__ row_ptr, const unsigned long long* __restrict__ chunkbuf,
        int* __restrict__ cur, int* __restrict__ edge_src) {
    int rel = blockIdx.y;
    int c = blockIdx.x >> 1, half = blockIdx.x & 1;
    const int* rp = row_ptr + rel * (N_NODES + 1);
    int lo = rp[c << 10];
    int hiN = min((c + 1) << 10, N_NODES);
    int hi = rp[hiN];
    const unsigned long long* cb = chunkbuf + (size_t)rel * N_EDGES;
    int* cu = cur + rel * N_NODES;
    int* es = edge_src + (size_t)rel * N_EDGES;
    for (int i = lo + half + 2 * (int)threadIdx.x; i < hi; i += 2 * 256) {
        unsigned long long pr = cb[i];
        int dn = (int)(pr & 0xffffffffu);
        int sn = (int)(pr >> 32);
        int pos = atomicAdd(&cu[dn], 1);
        es[pos] = sn;
    }
}

// sort each node's adjacency list by src
__global__ void sort_adj_kernel(const int* __restrict__ row_ptr, int* __restrict__ edge_src) {
    int i = blockIdx.x * 256 + threadIdx.x;
    if (i >= 3 * N_NODES) return;
    int rel = i / N_NODES, n = i - rel * N_NODES;
    const int* rp = row_ptr + rel * (N_NODES + 1);
    int* es = edge_src + rel * N_EDGES;
    int s0 = rp[n], s1 = rp[n + 1];
    for (int a = s0 + 1; a < s1; a++) {
        int key = es[a];
        int b = a - 1;
        while (b >= s0 && es[b] > key) { es[b + 1] = es[b]; b--; }
        es[b + 1] = key;
    }
}

// ---------------- Fused init: layer-1 weights + bf16 emb tables ----------------

__global__ void prep_init_kernel(const float* __restrict__ W1self, const float* __restrict__ W1neigh,
                                 unsigned short* __restrict__ Wbt1,
                                 const float* __restrict__ emb_h, const float* __restrict__ emb_p,
                                 const float* __restrict__ emb_hp,
                                 unsigned short* __restrict__ emb_bf) {
    if (blockIdx.x < 192) {
        int idx = blockIdx.x * 256 + threadIdx.x;
        int rel = idx / (H * 128), rem = idx % (H * 128);
        int c = rem / 128, k = rem % 128;
        float v = (k < 64) ? W1self[((size_t)rel * 64 + k) * H + c]
                           : W1neigh[((size_t)rel * 64 + (k - 64)) * H + c];
        Wbt1[idx] = f2b(v);
    } else {
        int i = (blockIdx.x - 192) * 256 + threadIdx.x;
        if (i >= 3 * 257 * EMB / 8) return;
        int rel = i / (257 * EMB / 8), j = i % (257 * EMB / 8);
        const float* emb = rel == 0 ? emb_h : (rel == 1 ? emb_p : emb_hp);
        const float* e = emb + (size_t)j * 8;
        unsigned short o[8];
#pragma unroll
        for (int k = 0; k < 8; k++) o[k] = f2b(e[k]);
        *(uint4*)&emb_bf[(size_t)rel * 257 * EMB + (size_t)j * 8] = *(uint4*)o;
    }
}

// ---------------- Layer-1 aggregation via emb tables (cache-resident) ----------------

__global__ __launch_bounds__(256) void aggregate1_kernel(
        const int* __restrict__ h_idx, const int* __restrict__ p_idx,
        const int* __restrict__ hp_idx,
        const unsigned short* __restrict__ emb_bf,
        const int* __restrict__ row_ptr, const int* __restrict__ edge_src,
        unsigned short* __restrict__ nmean) {
    const int TPN = 8;
    int rel = blockIdx.y;
    int node = blockIdx.x * 32 + threadIdx.x / TPN;
    int c8 = (threadIdx.x % TPN) * 8;
    if (node >= N_NODES) return;
    const int* idxarr = rel == 0 ? h_idx : (rel == 1 ? p_idx : hp_idx);
    const unsigned short* emb = emb_bf + (size_t)rel * 257 * EMB;
    const int* rp = row_ptr + rel * (N_NODES + 1);
    const int* es = edge_src + rel * N_EDGES;
    int s0 = rp[node], s1 = rp[node + 1];
    float acc[8];
#pragma unroll
    for (int j = 0; j < 8; j++) acc[j] = 0.f;

#define ACCUM(V)                                                                      \
    {                                                                                 \
        unsigned int w[4] = {(V).x, (V).y, (V).z, (V).w};                             \
        _Pragma("unroll") for (int j = 0; j < 4; j++) {                               \
            acc[2 * j] += __builtin_bit_cast(float, w[j] << 16);                      \
            acc[2 * j + 1] += __builtin_bit_cast(float, w[j] & 0xffff0000u);          \
        }                                                                             \
    }

    int e = s0;
    for (; e + 4 <= s1; e += 4) {
        int i0 = idxarr[es[e]], i1 = idxarr[es[e + 1]];
        int i2 = idxarr[es[e + 2]], i3 = idxarr[es[e + 3]];
        uint4 v0 = *(const uint4*)&emb[(size_t)i0 * EMB + c8];
        uint4 v1 = *(const uint4*)&emb[(size_t)i1 * EMB + c8];
        uint4 v2 = *(const uint4*)&emb[(size_t)i2 * EMB + c8];
        uint4 v3 = *(const uint4*)&emb[(size_t)i3 * EMB + c8];
        ACCUM(v0) ACCUM(v1) ACCUM(v2) ACCUM(v3)
    }
    for (; e < s1; e++) {
        uint4 v0 = *(const uint4*)&emb[(size_t)idxarr[es[e]] * EMB + c8];
        ACCUM(v0)
    }
    int deg = s1 - s0;
    float inv = 1.f / (float)max(deg, 1);
    unsigned short o[8];
#pragma unroll
    for (int j = 0; j < 8; j++)
        o[j] = (deg > 0) ? f2b(acc[j] * inv) : (unsigned short)0;
    *(uint4*)&nmean[((size_t)rel * N_NODES + node) * EMB + c8] = *(uint4*)o;
}

// ---------------- Layers 2-4 aggregation (48 nodes/block, 3 batches) ----------------

template <bool FOLD>
__global__ __launch_bounds__(256) void aggregate_kernel(
        const unsigned short* __restrict__ x,
        const int* __restrict__ row_ptr, const int* __restrict__ edge_src,
        const float* __restrict__ st,
        unsigned short* __restrict__ nmean) {
    const int TPN = 16;
    int rel = blockIdx.y;
    int c8 = (threadIdx.x % TPN) * 8;
    int nloc = threadIdx.x / TPN;
    const int* rp = row_ptr + rel * (N_NODES + 1);
    const int* es = edge_src + rel * N_EDGES;
    const unsigned short* xr = x + (size_t)rel * N_NODES * H;

    float sj[8], tj[8];
    if (FOLD) {
#pragma unroll
        for (int j = 0; j < 8; j++) {
            sj[j] = st[rel * 2 * H + c8 + j];
            tj[j] = st[rel * 2 * H + H + c8 + j];
        }
    }

#pragma unroll
    for (int batch = 0; batch < 3; batch++) {
        int node = blockIdx.x * 48 + batch * 16 + nloc;
        if (node >= N_NODES) continue;
        int s0 = rp[node], s1 = rp[node + 1];
        float acc[8];
#pragma unroll
        for (int j = 0; j < 8; j++) acc[j] = 0.f;
        int e = s0;
        for (; e + 4 <= s1; e += 4) {
            int i0 = es[e], i1 = es[e + 1], i2 = es[e + 2], i3 = es[e + 3];
            uint4 v0 = *(const uint4*)&xr[(size_t)i0 * H + c8];
            uint4 v1 = *(const uint4*)&xr[(size_t)i1 * H + c8];
            uint4 v2 = *(const uint4*)&xr[(size_t)i2 * H + c8];
            uint4 v3 = *(const uint4*)&xr[(size_t)i3 * H + c8];
            ACCUM(v0) ACCUM(v1) ACCUM(v2) ACCUM(v3)
        }
        for (; e < s1; e++) {
            uint4 v0 = *(const uint4*)&xr[(size_t)es[e] * H + c8];
            ACCUM(v0)
        }
        int deg = s1 - s0;
        float inv = 1.f / (float)max(deg, 1);
        unsigned short o[8];
#pragma unroll
        for (int j = 0; j < 8; j++) {
            float m = acc[j] * inv;
            if (FOLD) m = sj[j] * m + tj[j];
            o[j] = (deg > 0) ? f2b(m) : (unsigned short)0;
        }
        *(uint4*)&nmean[((size_t)rel * N_NODES + node) * H + c8] = *(uint4*)o;
    }
#undef ACCUM
}

// ---- MFMA GEMM (512 threads, 8 waves, LDS-staged, BK=64 chunks):
//      hp = PReLU([x|nmean]@Wbt^T + b); fp32 col stats (16-way striped);
//      per-graph readout fused (4-way striped); STORE=false skips hp write. ----

template <int KX, bool G1, bool STORE>
__global__ __launch_bounds__(512) void gemm_kernel(
        const unsigned short* __restrict__ x,
        const unsigned short* __restrict__ nmean,
        const unsigned short* __restrict__ Wbt,
        const float* __restrict__ bias,
        const float* __restrict__ alpha,
        unsigned short* __restrict__ out,
        float* __restrict__ statsR,               // [SREP][3][256]
        const int* __restrict__ seg_all,
        float* __restrict__ goutR,                // [GREP][GSZ]
        int layer,
        const unsigned short* __restrict__ embt,
        const int* __restrict__ h_idx, const int* __restrict__ p_idx,
        const int* __restrict__ hp_idx) {
    const int KTOT = 2 * KX;
    const int NCH = KTOT / 64;                    // 64-wide K chunks
    int rel = blockIdx.y;
    int row0 = blockIdx.x * 128;
    const unsigned short* xr = x + (size_t)rel * N_NODES * KX;
    const unsigned short* nm = nmean + (size_t)rel * N_NODES * KX;
    const unsigned short* W = Wbt + (size_t)rel * H * KTOT;
    unsigned short* o = out + (size_t)rel * N_NODES * H;
    float* stats = statsR + (size_t)(blockIdx.x & (SREP - 1)) * 768;
    float* gout = goutR + (size_t)(blockIdx.x & (GREP - 1)) * GSZ;

    __shared__ __align__(16) short At[128][72];
    __shared__ __align__(16) short Bt[128][72];

    int tid = threadIdx.x;
    int lane = tid & 63;
    int wave = tid >> 6;          // 0..7
    int wr = wave >> 2;           // 0..1 (row half)
    int wcq = wave & 3;           // 0..3 (32-col strip)
    int l15 = lane & 15;
    int koff = (lane >> 4) * 8;

    f32x4 acc[4][2];
#pragma unroll
    for (int m = 0; m < 4; m++)
#pragma unroll
        for (int n = 0; n < 2; n++) acc[m][n] = (f32x4){0.f, 0.f, 0.f, 0.f};

    int seg = tid & 3;
    int rloc = tid >> 2;          // 0..127 (one staged row per thread)

    int nid0 = 0;
    if (G1) {
        const int* idxarr = rel == 0 ? h_idx : (rel == 1 ? p_idx : hp_idx);
        if (row0 + rloc < N_NODES) nid0 = idxarr[row0 + rloc];
    }
    const unsigned short* et = G1 ? (embt + (size_t)rel * 257 * EMB) : nullptr;

    for (int ch = 0; ch < NCH; ch++) {
        int kc = ch * 64;
        const bool selfh = kc < KX;
        const unsigned short* Asrc = selfh ? xr : nm;
        int kb = selfh ? kc : kc - KX;
        {
            int gr = row0 + rloc;
            uint4 v0 = make_uint4(0u, 0u, 0u, 0u), v1 = v0;
            if (gr < N_NODES) {
                if (G1 && selfh) {
                    v0 = *(const uint4*)&et[(size_t)nid0 * EMB + kb + seg * 8];
                    v1 = *(const uint4*)&et[(size_t)nid0 * EMB + kb + 32 + seg * 8];
                } else {
                    v0 = *(const uint4*)&Asrc[(size_t)gr * KX + kb + seg * 8];
                    v1 = *(const uint4*)&Asrc[(size_t)gr * KX + kb + 32 + seg * 8];
                }
            }
            *(uint4*)&At[rloc][seg * 8] = v0;
            *(uint4*)&At[rloc][32 + seg * 8] = v1;
            *(uint4*)&Bt[rloc][seg * 8] = *(const uint4*)&W[(size_t)rloc * KTOT + kc + seg * 8];
            *(uint4*)&Bt[rloc][32 + seg * 8] = *(const uint4*)&W[(size_t)rloc * KTOT + kc + 32 + seg * 8];
        }
        __syncthreads();
#pragma unroll
        for (int kk = 0; kk < 64; kk += 32) {
            bf16x8 a[4], b[2];
#pragma unroll
            for (int m = 0; m < 4; m++) a[m] = *(const bf16x8*)&At[wr * 64 + m * 16 + l15][kk + koff];
#pragma unroll
            for (int n = 0; n < 2; n++) b[n] = *(const bf16x8*)&Bt[wcq * 32 + n * 16 + l15][kk + koff];
#pragma unroll
            for (int m = 0; m < 4; m++)
#pragma unroll
                for (int n = 0; n < 2; n++)
                    acc[m][n] = __builtin_amdgcn_mfma_f32_16x16x32_bf16(a[m], b[n], acc[m][n], 0, 0, 0);
        }
        __syncthreads();
    }

    float bs[2], as_[2];
#pragma unroll
    for (int n = 0; n < 2; n++) {
        int col = wcq * 32 + n * 16 + l15;
        bs[n] = bias[rel * H + col];
        as_[n] = alpha[rel * H + col];
    }
    const int* sg = seg_all + rel * N_NODES;
    float csum[2] = {0.f, 0.f}, cssq[2] = {0.f, 0.f};
    int curg = -1;
    float run[2] = {0.f, 0.f};
    int rbase = row0 + wr * 64 + (lane >> 4) * 4;
#pragma unroll
    for (int m = 0; m < 4; m++) {
#pragma unroll
        for (int j = 0; j < 4; j++) {
            int r = rbase + m * 16 + j;
            if (r >= N_NODES) continue;
            int g = sg[r];
            if (g != curg) {
                if (curg >= 0) {
                    float* ob = gout + (size_t)curg * (3 * 4 * H) + rel * (4 * H) + layer * H + wcq * 32 + l15;
#pragma unroll
                    for (int n = 0; n < 2; n++) { atomicAdd(ob + n * 16, run[n]); run[n] = 0.f; }
                }
                curg = g;
            }
#pragma unroll
            for (int n = 0; n < 2; n++) {
                float v = acc[m][n][j] + bs[n];
                v = v > 0.f ? v : as_[n] * v;
                if (STORE) o[(size_t)r * H + wcq * 32 + n * 16 + l15] = f2b(v);
                csum[n] += v;
                cssq[n] += v * v;
                run[n] += v;
            }
        }
    }
    if (curg >= 0) {
        float* ob = gout + (size_t)curg * (3 * 4 * H) + rel * (4 * H) + layer * H + wcq * 32 + l15;
#pragma unroll
        for (int n = 0; n < 2; n++) atomicAdd(ob + n * 16, run[n]);
    }
    __syncthreads();
    float* smS = (float*)&At[0][0];   // 128 cols x 8 contributors = 4 KB
    float* smQ = (float*)&Bt[0][0];
    int contrib = wr * 4 + (lane >> 4);
#pragma unroll
    for (int n = 0; n < 2; n++) {
        int col = wcq * 32 + n * 16 + l15;
        smS[col * 8 + contrib] = csum[n];
        smQ[col * 8 + contrib] = cssq[n];
    }
    __syncthreads();
    if (tid < 128) {
        float s = 0.f, q = 0.f;
#pragma unroll
        for (int i = 0; i < 8; i++) { s += smS[tid * 8 + i]; q += smQ[tid * 8 + i]; }
        atomicAdd(&stats[rel * 256 + tid], s);
        atomicAdd(&stats[rel * 256 + 128 + tid], q);
    }
}

// ---------------- BN stats (sum 16 replicas) -> affine (s,t); zero replicas ----------------

__global__ void finalize_kernel(float* __restrict__ statsR,
                                const float* __restrict__ gamma, const float* __restrict__ beta,
                                float* __restrict__ st) {
    int rel = blockIdx.x, c = threadIdx.x;
    float sum = 0.f, ssq = 0.f;
#pragma unroll
    for (int k = 0; k < SREP; k++) {
        sum += statsR[(size_t)k * 768 + rel * 256 + c];
        ssq += statsR[(size_t)k * 768 + rel * 256 + 128 + c];
        statsR[(size_t)k * 768 + rel * 256 + c] = 0.f;
        statsR[(size_t)k * 768 + rel * 256 + 128 + c] = 0.f;
    }
    const float invN = 1.f / N_NODES;
    float mu = sum * invN;
    float var = ssq * invN - mu * mu;
    float s = gamma[rel * H + c] * rsqrtf(var + EPS);
    st[rel * 2 * H + c] = s;
    st[rel * 2 * H + H + c] = beta[rel * H + c] - mu * s;
}

// ---------------- Weight prep (layers 2-4) ----------------

__global__ void prep_kernel(const float* __restrict__ Wself, const float* __restrict__ Wneigh,
                            const float* __restrict__ b, const float* __restrict__ st,
                            unsigned short* __restrict__ Wbt, float* __restrict__ biasp) {
    if (blockIdx.x < 384) {
        int idx = blockIdx.x * 256 + threadIdx.x;
        int rel = idx / (H * 256), rem = idx % (H * 256);
        int c = rem / 256, k = rem % 256;
        float v;
        if (k < 128) v = st[rel * 2 * H + k] * Wself[((size_t)rel * H + k) * H + c];
        else         v = Wneigh[((size_t)rel * H + (k - 128)) * H + c];
        Wbt[idx] = f2b(v);
    } else if (threadIdx.x < H) {
        int rel = blockIdx.x - 384, c = threadIdx.x;
        const float* t = st + rel * 2 * H + H;
        float s = b[rel * H + c];
        for (int k = 0; k < H; k++) s += t[k] * Wself[((size_t)rel * H + k) * H + c];
        biasp[rel * H + c] = s;
    }
}

// ---------------- Final: sum gout replicas, mean + BN affine ----------------

__global__ void scale_out_kernel(float* __restrict__ out, const float* __restrict__ goutR,
                                 const int* __restrict__ seg,
                                 const float* __restrict__ st_all) {
    int i = blockIdx.x * 256 + threadIdx.x;
    if (i >= GSZ) return;
    int g = i / (3 * 4 * H), k = i % (3 * 4 * H);
    int rel = k / (4 * H), rem = k % (4 * H), layer = rem / H, c = rem % H;
    const int* sg = seg + rel * N_NODES;
    int lo = 0, hi = N_NODES;
    while (lo < hi) { int m = (lo + hi) >> 1; if (sg[m] < g) lo = m + 1; else hi = m; }
    int start = lo;
    hi = N_NODES;
    while (lo < hi) { int m = (lo + hi) >> 1; if (sg[m] <= g) lo = m + 1; else hi = m; }
    int cnt = lo - start;
    float sum = 0.f;
#pragma unroll
    for (int r = 0; r < GREP; r++) sum += goutR[(size_t)r * GSZ + i];
    float mean = sum / (float)max(cnt, 1);
    const float* st = st_all + ((size_t)layer * 3 + rel) * 2 * H;
    out[i] = st[c] * mean + st[H + c];
}

// ---------------- Orchestration ----------------

extern "C" void kernel_launch(void* const* d_in, const int* in_sizes, int n_in,
                              void* d_out, int out_size, void* d_ws, size_t ws_size,
                              hipStream_t stream) {
    const int* h_idx = (const int*)d_in[0];
    const int* p_idx = (const int*)d_in[1];
    const int* hp_idx = (const int*)d_in[2];
    const int* src = (const int*)d_in[3];
    const int* dst = (const int*)d_in[4];
    const int* seg = (const int*)d_in[5];
    const float* emb_h = (const float*)d_in[6];
    const float* emb_p = (const float*)d_in[7];
    const float* emb_hp = (const float*)d_in[8];
    const float* W1_self = (const float*)d_in[9];
    const float* W1_neigh = (const float*)d_in[10];
    const float* b1 = (const float*)d_in[11];
    const float* a1 = (const float*)d_in[12];
    const float* gamma1 = (const float*)d_in[13];
    const float* beta1 = (const float*)d_in[14];
    const float* W_self = (const float*)d_in[15];
    const float* W_neigh = (const float*)d_in[16];
    const float* b = (const float*)d_in[17];
    const float* a = (const float*)d_in[18];
    const float* gamma = (const float*)d_in[19];
    const float* beta = (const float*)d_in[20];
    float* out = (float*)d_out;

    // workspace
    char* p = (char*)d_ws;
    unsigned short* hpA = (unsigned short*)p; p += (size_t)3 * N_NODES * H * 2;
    unsigned short* hpB = (unsigned short*)p; p += (size_t)3 * N_NODES * H * 2;
    unsigned short* Wbt1 = (unsigned short*)p; p += (size_t)3 * H * 128 * 2;
    unsigned short* Wbt = (unsigned short*)p; p += (size_t)3 * H * 256 * 2;
    unsigned short* emb_bf = (unsigned short*)p; p += (size_t)3 * 257 * EMB * 2;
    float* biasp = (float*)p; p += 3 * H * sizeof(float);
    float* st_all = (float*)p; p += 4 * 3 * 2 * H * sizeof(float);
    float* statsR = (float*)p; p += (size_t)SREP * 768 * sizeof(float);
    float* goutR = (float*)p; p += (size_t)GREP * GSZ * sizeof(float);
    int* deg = (int*)p; p += (size_t)3 * N_NODES * 4;
    int* row_ptr = (int*)p; p += (size_t)3 * (N_NODES + 1) * 4;
    int* cur = (int*)p; p += (size_t)3 * N_NODES * 4;
    int* gcur = (int*)p; p += (size_t)3 * NCH2 * 4;
    int* ctot = (int*)p; p += (size_t)3 * SCH * 4;
    int* edge_src = (int*)p; p += (size_t)3 * N_EDGES * 4;
    unsigned long long* chunkbuf = (unsigned long long*)p; p += (size_t)3 * N_EDGES * 8;

    hipMemsetAsync(statsR, 0, (size_t)SREP * 768 * 4, stream);
    hipMemsetAsync(goutR, 0, (size_t)GREP * GSZ * 4, stream);

    // CSR build: count -> 3-stage parallel scan -> partition -> place -> sort
    hipMemsetAsync(deg, 0, (size_t)3 * N_NODES * 4, stream);
    dim3 eb((N_EDGES + 255) / 256, 3);
    count_deg_kernel<<<eb, 256, 0, stream>>>(dst, deg);
    local_scan_kernel<<<dim3(SCH, 3), 1024, 0, stream>>>(deg, row_ptr, ctot);
    chunk_scan_kernel<<<3, 32, 0, stream>>>(ctot, row_ptr);
    fixup_kernel<<<(3 * N_NODES + 255) / 256, 256, 0, stream>>>(row_ptr, ctot, cur, gcur);
    partA_kernel<<<dim3(NSLA, 3), 256, 0, stream>>>(src, dst, gcur, chunkbuf);
    fillB_kernel<<<dim3(2 * NCH2, 3), 256, 0, stream>>>(row_ptr, chunkbuf, cur, edge_src);
    sort_adj_kernel<<<(3 * N_NODES + 255) / 256, 256, 0, stream>>>(row_ptr, edge_src);

    prep_init_kernel<<<217, 256, 0, stream>>>(W1_self, W1_neigh, Wbt1,
                                              emb_h, emb_p, emb_hp, emb_bf);

    dim3 gemm_grid((N_NODES + 127) / 128, 3);
    dim3 agg_grid((N_NODES + 47) / 48, 3);

    // ---- layer 1 (K = 64; nmean ld=64 in hpB via emb-table gather; out hpA) ----
    aggregate1_kernel<<<dim3((N_NODES + 31) / 32, 3), 256, 0, stream>>>(
        h_idx, p_idx, hp_idx, emb_bf, row_ptr, edge_src, hpB);
    gemm_kernel<64, true, true><<<gemm_grid, 512, 0, stream>>>(
        emb_bf /*unused*/, hpB, Wbt1, b1, a1, hpA, statsR, seg, goutR, 0,
        emb_bf, h_idx, p_idx, hp_idx);
    finalize_kernel<<<3, H, 0, stream>>>(statsR, gamma1, beta1, st_all);

    // ---- layers 2-4 (K = 128; out aliases nmean; last layer skips hp store) ----
    unsigned short* xin = hpA;
    unsigned short* xout = hpB;
    for (int l = 0; l < 3; l++) {
        const float* st_prev = st_all + (size_t)l * 3 * 2 * H;
        prep_kernel<<<387, 256, 0, stream>>>(
            W_self + (size_t)l * 3 * H * H, W_neigh + (size_t)l * 3 * H * H,
            b + (size_t)l * 3 * H, st_prev, Wbt, biasp);
        aggregate_kernel<true><<<agg_grid, 256, 0, stream>>>(
            xin, row_ptr, edge_src, st_prev, xout);
        if (l < 2)
            gemm_kernel<128, false, true><<<gemm_grid, 512, 0, stream>>>(
                xin, xout, Wbt, biasp, a + (size_t)l * 3 * H, xout, statsR, seg, goutR, l + 1,
                nullptr, nullptr, nullptr, nullptr);
        else
            gemm_kernel<128, false, false><<<gemm_grid, 512, 0, stream>>>(
                xin, xout, Wbt, biasp, a + (size_t)l * 3 * H, xout, statsR, seg, goutR, l + 1,
                nullptr, nullptr, nullptr, nullptr);
        finalize_kernel<<<3, H, 0, stream>>>(
            statsR, gamma + (size_t)l * 3 * H, beta + (size_t)l * 3 * H,
            st_all + (size_t)(l + 1) * 3 * 2 * H);
        unsigned short* t = xin; xin = xout; xout = t;
    }

    scale_out_kernel<<<(GSZ + 255) / 256, 256, 0, stream>>>(out, goutR, seg, st_all);
}

// Round 21
// 534.992 us; speedup vs baseline: 1.3422x; 1.0058x over previous
//
#include <hip/hip_runtime.h>

#define N_NODES 50000
#define N_EDGES 400000
#define N_GRAPHS 64
#define EMB 64
#define H 128
#define EPS 1e-5f

#define NCH2 49            // dst chunks of 1024 nodes
#define NSLA 48            // partition slices
#define SREP 16            // stats replicas
#define GREP 4             // gout replicas
#define GSZ (N_GRAPHS * 3 * 4 * H)
#define SCH 13             // scan chunks of 4096

typedef __attribute__((ext_vector_type(8))) short bf16x8;
typedef __attribute__((ext_vector_type(4))) float f32x4;

__device__ __forceinline__ unsigned short f2b(float f) {
    unsigned int u = __builtin_bit_cast(unsigned int, f);
    unsigned int r = (u + 0x7fff + ((u >> 16) & 1)) >> 16;  // RNE
    return (unsigned short)r;
}

// ---------------- CSR build ----------------

__global__ void count_deg_kernel(const int* __restrict__ dst, int* __restrict__ deg) {
    int rel = blockIdx.y;
    int e = blockIdx.x * 256 + threadIdx.x;
    if (e < N_EDGES) atomicAdd(&deg[rel * N_NODES + dst[rel * N_EDGES + e]], 1);
}

// parallel scan, stage 1: per-chunk (4096) exclusive prefix + chunk totals
__global__ void local_scan_kernel(const int* __restrict__ deg, int* __restrict__ row_ptr,
                                  int* __restrict__ ctot) {
    int rel = blockIdx.y, chunk = blockIdx.x;
    int base = chunk * 4096;
    const int* d = deg + rel * N_NODES;
    int* rp = row_ptr + rel * (N_NODES + 1);
    __shared__ int sm[1024];
    int i0 = base + (int)threadIdx.x * 4;
    int v[4];
    int s = 0;
#pragma unroll
    for (int k = 0; k < 4; k++) { v[k] = (i0 + k < N_NODES) ? d[i0 + k] : 0; s += v[k]; }
    sm[threadIdx.x] = s;
    __syncthreads();
    for (int off = 1; off < 1024; off <<= 1) {
        int t = (threadIdx.x >= off) ? sm[threadIdx.x - off] : 0;
        __syncthreads();
        sm[threadIdx.x] += t;
        __syncthreads();
    }
    int run = sm[threadIdx.x] - s;   // exclusive within chunk
#pragma unroll
    for (int k = 0; k < 4; k++) {
        if (i0 + k < N_NODES) rp[i0 + k] = run;
        run += v[k];
    }
    if (threadIdx.x == 1023) ctot[rel * SCH + chunk] = sm[1023];
}

// stage 2: scan the 13 chunk totals per rel (in place -> exclusive offsets)
__global__ void chunk_scan_kernel(int* __restrict__ ctot, int* __restrict__ row_ptr) {
    int rel = blockIdx.x;
    if (threadIdx.x == 0) {
        int run = 0;
        for (int c = 0; c < SCH; c++) { int t = ctot[rel * SCH + c]; ctot[rel * SCH + c] = run; run += t; }
        row_ptr[rel * (N_NODES + 1) + N_NODES] = run;
    }
}

// stage 3: add chunk offsets; write cur and per-1024-chunk cursors gcur
__global__ void fixup_kernel(int* __restrict__ row_ptr, const int* __restrict__ ctot,
                             int* __restrict__ cur, int* __restrict__ gcur) {
    int i = blockIdx.x * 256 + threadIdx.x;
    if (i >= 3 * N_NODES) return;
    int rel = i / N_NODES, n = i - rel * N_NODES;
    int val = row_ptr[rel * (N_NODES + 1) + n] + ctot[rel * SCH + (n >> 12)];
    row_ptr[rel * (N_NODES + 1) + n] = val;
    cur[rel * N_NODES + n] = val;
    if ((n & 1023) == 0) gcur[rel * NCH2 + (n >> 10)] = val;
}

// Phase A: partition edges into dst-chunk-major staging buffer (contiguous runs)
__global__ __launch_bounds__(256) void partA_kernel(
        const int* __restrict__ src, const int* __restrict__ dst,
        int* __restrict__ gcur, unsigned long long* __restrict__ chunkbuf) {
    int rel = blockIdx.y;
    const int* ds = dst + (size_t)rel * N_EDGES;
    const int* ss = src + (size_t)rel * N_EDGES;
    unsigned long long* cb = chunkbuf + (size_t)rel * N_EDGES;
    __shared__ int cnt[NCH2];
    __shared__ int lcur[NCH2];
    int tid = threadIdx.x;
    if (tid < NCH2) cnt[tid] = 0;
    __syncthreads();
    for (int e = blockIdx.x * 256 + tid; e < N_EDGES; e += NSLA * 256)
        atomicAdd(&cnt[ds[e] >> 10], 1);
    __syncthreads();
    if (tid < NCH2) lcur[tid] = atomicAdd(&gcur[rel * NCH2 + tid], cnt[tid]);
    __syncthreads();
    for (int e = blockIdx.x * 256 + tid; e < N_EDGES; e += NSLA * 256) {
        int dn = ds[e], sn = ss[e];
        int idx = atomicAdd(&lcur[dn >> 10], 1);
        cb[idx] = ((unsigned long long)(unsigned)sn << 32) | (unsigned)dn;
    }
}

// Phase B: each chunk's region placed by 4 blocks
__global__ __launch_bounds__(256) void fillB_kernel(
        const int* __restrict__ row_ptr, const unsigned long long* __restrict__ chunkbuf,
        int* __restrict__ cur, int* __restrict__ edge_src) {
    int rel = blockIdx.y;
    int c = blockIdx.x >> 2, quarter = blockIdx.x & 3;
    const int* rp = row_ptr + rel * (N_NODES + 1);
    int lo = rp[c << 10];
    int hiN = min((c + 1) << 10, N_NODES);
    int hi = rp[hiN];
    const unsigned long long* cb = chunkbuf + (size_t)rel * N_EDGES;
    int* cu = cur + rel * N_NODES;
    int* es = edge_src + (size_t)rel * N_EDGES;
    for (int i = lo + quarter + 4 * (int)threadIdx.x; i < hi; i += 4 * 256) {
        unsigned long long pr = cb[i];
        int dn = (int)(pr & 0xffffffffu);
        int sn = (int)(pr >> 32);
        int pos = atomicAdd(&cu[dn], 1);
        es[pos] = sn;
    }
}

// sort each node's adjacency list by src
__global__ void sort_adj_kernel(const int* __restrict__ row_ptr, int* __restrict__ edge_src) {
    int i = blockIdx.x * 256 + threadIdx.x;
    if (i >= 3 * N_NODES) return;
    int rel = i / N_NODES, n = i - rel * N_NODES;
    const int* rp = row_ptr + rel * (N_NODES + 1);
    int* es = edge_src + rel * N_EDGES;
    int s0 = rp[n], s1 = rp[n + 1];
    for (int a = s0 + 1; a < s1; a++) {
        int key = es[a];
        int b = a - 1;
        while (b >= s0 && es[b] > key) { es[b + 1] = es[b]; b--; }
        es[b + 1] = key;
    }
}

// ---------------- Fused init: layer-1 weights + bf16 emb tables ----------------

__global__ void prep_init_kernel(const float* __restrict__ W1self, const float* __restrict__ W1neigh,
                                 unsigned short* __restrict__ Wbt1,
                                 const float* __restrict__ emb_h, const float* __restrict__ emb_p,
                                 const float* __restrict__ emb_hp,
                                 unsigned short* __restrict__ emb_bf) {
    if (blockIdx.x < 192) {
        int idx = blockIdx.x * 256 + threadIdx.x;
        int rel = idx / (H * 128), rem = idx % (H * 128);
        int c = rem / 128, k = rem % 128;
        float v = (k < 64) ? W1self[((size_t)rel * 64 + k) * H + c]
                           : W1neigh[((size_t)rel * 64 + (k - 64)) * H + c];
        Wbt1[idx] = f2b(v);
    } else {
        int i = (blockIdx.x - 192) * 256 + threadIdx.x;
        if (i >= 3 * 257 * EMB / 8) return;
        int rel = i / (257 * EMB / 8), j = i % (257 * EMB / 8);
        const float* emb = rel == 0 ? emb_h : (rel == 1 ? emb_p : emb_hp);
        const float* e = emb + (size_t)j * 8;
        unsigned short o[8];
#pragma unroll
        for (int k = 0; k < 8; k++) o[k] = f2b(e[k]);
        *(uint4*)&emb_bf[(size_t)rel * 257 * EMB + (size_t)j * 8] = *(uint4*)o;
    }
}

// ---------------- Layer-1 aggregation via emb tables (cache-resident) ----------------

__global__ __launch_bounds__(256) void aggregate1_kernel(
        const int* __restrict__ h_idx, const int* __restrict__ p_idx,
        const int* __restrict__ hp_idx,
        const unsigned short* __restrict__ emb_bf,
        const int* __restrict__ row_ptr, const int* __restrict__ edge_src,
        unsigned short* __restrict__ nmean) {
    const int TPN = 8;
    int rel = blockIdx.y;
    int node = blockIdx.x * 32 + threadIdx.x / TPN;
    int c8 = (threadIdx.x % TPN) * 8;
    if (node >= N_NODES) return;
    const int* idxarr = rel == 0 ? h_idx : (rel == 1 ? p_idx : hp_idx);
    const unsigned short* emb = emb_bf + (size_t)rel * 257 * EMB;
    const int* rp = row_ptr + rel * (N_NODES + 1);
    const int* es = edge_src + rel * N_EDGES;
    int s0 = rp[node], s1 = rp[node + 1];
    float acc[8];
#pragma unroll
    for (int j = 0; j < 8; j++) acc[j] = 0.f;

#define ACCUM(V)                                                                      \
    {                                                                                 \
        unsigned int w[4] = {(V).x, (V).y, (V).z, (V).w};                             \
        _Pragma("unroll") for (int j = 0; j < 4; j++) {                               \
            acc[2 * j] += __builtin_bit_cast(float, w[j] << 16);                      \
            acc[2 * j + 1] += __builtin_bit_cast(float, w[j] & 0xffff0000u);          \
        }                                                                             \
    }

    int e = s0;
    for (; e + 4 <= s1; e += 4) {
        int i0 = idxarr[es[e]], i1 = idxarr[es[e + 1]];
        int i2 = idxarr[es[e + 2]], i3 = idxarr[es[e + 3]];
        uint4 v0 = *(const uint4*)&emb[(size_t)i0 * EMB + c8];
        uint4 v1 = *(const uint4*)&emb[(size_t)i1 * EMB + c8];
        uint4 v2 = *(const uint4*)&emb[(size_t)i2 * EMB + c8];
        uint4 v3 = *(const uint4*)&emb[(size_t)i3 * EMB + c8];
        ACCUM(v0) ACCUM(v1) ACCUM(v2) ACCUM(v3)
    }
    for (; e < s1; e++) {
        uint4 v0 = *(const uint4*)&emb[(size_t)idxarr[es[e]] * EMB + c8];
        ACCUM(v0)
    }
    int deg = s1 - s0;
    float inv = 1.f / (float)max(deg, 1);
    unsigned short o[8];
#pragma unroll
    for (int j = 0; j < 8; j++)
        o[j] = (deg > 0) ? f2b(acc[j] * inv) : (unsigned short)0;
    *(uint4*)&nmean[((size_t)rel * N_NODES + node) * EMB + c8] = *(uint4*)o;
}

// ---------------- Layers 2-4 aggregation (32 nodes/block, 2 batches) ----------------

template <bool FOLD>
__global__ __launch_bounds__(256) void aggregate_kernel(
        const unsigned short* __restrict__ x,
        const int* __restrict__ row_ptr, const int* __restrict__ edge_src,
        const float* __restrict__ st,
        unsigned short* __restrict__ nmean) {
    const int TPN = 16;
    int rel = blockIdx.y;
    int c8 = (threadIdx.x % TPN) * 8;
    int nloc = threadIdx.x / TPN;
    const int* rp = row_ptr + rel * (N_NODES + 1);
    const int* es = edge_src + rel * N_EDGES;
    const unsigned short* xr = x + (size_t)rel * N_NODES * H;

    float sj[8], tj[8];
    if (FOLD) {
#pragma unroll
        for (int j = 0; j < 8; j++) {
            sj[j] = st[rel * 2 * H + c8 + j];
            tj[j] = st[rel * 2 * H + H + c8 + j];
        }
    }

#pragma unroll
    for (int batch = 0; batch < 2; batch++) {
        int node = blockIdx.x * 32 + batch * 16 + nloc;
        if (node >= N_NODES) continue;
        int s0 = rp[node], s1 = rp[node + 1];
        float acc[8];
#pragma unroll
        for (int j = 0; j < 8; j++) acc[j] = 0.f;
        int e = s0;
        for (; e + 4 <= s1; e += 4) {
            int i0 = es[e], i1 = es[e + 1], i2 = es[e + 2], i3 = es[e + 3];
            uint4 v0 = *(const uint4*)&xr[(size_t)i0 * H + c8];
            uint4 v1 = *(const uint4*)&xr[(size_t)i1 * H + c8];
            uint4 v2 = *(const uint4*)&xr[(size_t)i2 * H + c8];
            uint4 v3 = *(const uint4*)&xr[(size_t)i3 * H + c8];
            ACCUM(v0) ACCUM(v1) ACCUM(v2) ACCUM(v3)
        }
        for (; e < s1; e++) {
            uint4 v0 = *(const uint4*)&xr[(size_t)es[e] * H + c8];
            ACCUM(v0)
        }
        int deg = s1 - s0;
        float inv = 1.f / (float)max(deg, 1);
        unsigned short o[8];
#pragma unroll
        for (int j = 0; j < 8; j++) {
            float m = acc[j] * inv;
            if (FOLD) m = sj[j] * m + tj[j];
            o[j] = (deg > 0) ? f2b(m) : (unsigned short)0;
        }
        *(uint4*)&nmean[((size_t)rel * N_NODES + node) * H + c8] = *(uint4*)o;
    }
#undef ACCUM
}

// ---- MFMA GEMM (512 threads, 8 waves, LDS-staged, BK=64 chunks):
//      hp = PReLU([x|nmean]@Wbt^T + b); fp32 col stats (16-way striped);
//      per-graph readout fused (4-way striped); STORE=false skips hp write. ----

template <int KX, bool G1, bool STORE>
__global__ __launch_bounds__(512) void gemm_kernel(
        const unsigned short* __restrict__ x,
        const unsigned short* __restrict__ nmean,
        const unsigned short* __restrict__ Wbt,
        const float* __restrict__ bias,
        const float* __restrict__ alpha,
        unsigned short* __restrict__ out,
        float* __restrict__ statsR,               // [SREP][3][256]
        const int* __restrict__ seg_all,
        float* __restrict__ goutR,                // [GREP][GSZ]
        int layer,
        const unsigned short* __restrict__ embt,
        const int* __restrict__ h_idx, const int* __restrict__ p_idx,
        const int* __restrict__ hp_idx) {
    const int KTOT = 2 * KX;
    const int NCH = KTOT / 64;                    // 64-wide K chunks
    int rel = blockIdx.y;
    int row0 = blockIdx.x * 128;
    const unsigned short* xr = x + (size_t)rel * N_NODES * KX;
    const unsigned short* nm = nmean + (size_t)rel * N_NODES * KX;
    const unsigned short* W = Wbt + (size_t)rel * H * KTOT;
    unsigned short* o = out + (size_t)rel * N_NODES * H;
    float* stats = statsR + (size_t)(blockIdx.x & (SREP - 1)) * 768;
    float* gout = goutR + (size_t)(blockIdx.x & (GREP - 1)) * GSZ;

    __shared__ __align__(16) short At[128][72];
    __shared__ __align__(16) short Bt[128][72];

    int tid = threadIdx.x;
    int lane = tid & 63;
    int wave = tid >> 6;          // 0..7
    int wr = wave >> 2;           // 0..1 (row half)
    int wcq = wave & 3;           // 0..3 (32-col strip)
    int l15 = lane & 15;
    int koff = (lane >> 4) * 8;

    f32x4 acc[4][2];
#pragma unroll
    for (int m = 0; m < 4; m++)
#pragma unroll
        for (int n = 0; n < 2; n++) acc[m][n] = (f32x4){0.f, 0.f, 0.f, 0.f};

    int seg = tid & 3;
    int rloc = tid >> 2;          // 0..127 (one staged row per thread)

    int nid0 = 0;
    if (G1) {
        const int* idxarr = rel == 0 ? h_idx : (rel == 1 ? p_idx : hp_idx);
        if (row0 + rloc < N_NODES) nid0 = idxarr[row0 + rloc];
    }
    const unsigned short* et = G1 ? (embt + (size_t)rel * 257 * EMB) : nullptr;

    for (int ch = 0; ch < NCH; ch++) {
        int kc = ch * 64;
        const bool selfh = kc < KX;
        const unsigned short* Asrc = selfh ? xr : nm;
        int kb = selfh ? kc : kc - KX;
        {
            int gr = row0 + rloc;
            uint4 v0 = make_uint4(0u, 0u, 0u, 0u), v1 = v0;
            if (gr < N_NODES) {
                if (G1 && selfh) {
                    v0 = *(const uint4*)&et[(size_t)nid0 * EMB + kb + seg * 8];
                    v1 = *(const uint4*)&et[(size_t)nid0 * EMB + kb + 32 + seg * 8];
                } else {
                    v0 = *(const uint4*)&Asrc[(size_t)gr * KX + kb + seg * 8];
                    v1 = *(const uint4*)&Asrc[(size_t)gr * KX + kb + 32 + seg * 8];
                }
            }
            *(uint4*)&At[rloc][seg * 8] = v0;
            *(uint4*)&At[rloc][32 + seg * 8] = v1;
            *(uint4*)&Bt[rloc][seg * 8] = *(const uint4*)&W[(size_t)rloc * KTOT + kc + seg * 8];
            *(uint4*)&Bt[rloc][32 + seg * 8] = *(const uint4*)&W[(size_t)rloc * KTOT + kc + 32 + seg * 8];
        }
        __syncthreads();
#pragma unroll
        for (int kk = 0; kk < 64; kk += 32) {
            bf16x8 a[4], b[2];
#pragma unroll
            for (int m = 0; m < 4; m++) a[m] = *(const bf16x8*)&At[wr * 64 + m * 16 + l15][kk + koff];
#pragma unroll
            for (int n = 0; n < 2; n++) b[n] = *(const bf16x8*)&Bt[wcq * 32 + n * 16 + l15][kk + koff];
#pragma unroll
            for (int m = 0; m < 4; m++)
#pragma unroll
                for (int n = 0; n < 2; n++)
                    acc[m][n] = __builtin_amdgcn_mfma_f32_16x16x32_bf16(a[m], b[n], acc[m][n], 0, 0, 0);
        }
        __syncthreads();
    }

    float bs[2], as_[2];
#pragma unroll
    for (int n = 0; n < 2; n++) {
        int col = wcq * 32 + n * 16 + l15;
        bs[n] = bias[rel * H + col];
        as_[n] = alpha[rel * H + col];
    }
    const int* sg = seg_all + rel * N_NODES;
    float csum[2] = {0.f, 0.f}, cssq[2] = {0.f, 0.f};
    int curg = -1;
    float run[2] = {0.f, 0.f};
    int rbase = row0 + wr * 64 + (lane >> 4) * 4;
#pragma unroll
    for (int m = 0; m < 4; m++) {
#pragma unroll
        for (int j = 0; j < 4; j++) {
            int r = rbase + m * 16 + j;
            if (r >= N_NODES) continue;
            int g = sg[r];
            if (g != curg) {
                if (curg >= 0) {
                    float* ob = gout + (size_t)curg * (3 * 4 * H) + rel * (4 * H) + layer * H + wcq * 32 + l15;
#pragma unroll
                    for (int n = 0; n < 2; n++) { atomicAdd(ob + n * 16, run[n]); run[n] = 0.f; }
                }
                curg = g;
            }
#pragma unroll
            for (int n = 0; n < 2; n++) {
                float v = acc[m][n][j] + bs[n];
                v = v > 0.f ? v : as_[n] * v;
                if (STORE) o[(size_t)r * H + wcq * 32 + n * 16 + l15] = f2b(v);
                csum[n] += v;
                cssq[n] += v * v;
                run[n] += v;
            }
        }
    }
    if (curg >= 0) {
        float* ob = gout + (size_t)curg * (3 * 4 * H) + rel * (4 * H) + layer * H + wcq * 32 + l15;
#pragma unroll
        for (int n = 0; n < 2; n++) atomicAdd(ob + n * 16, run[n]);
    }
    __syncthreads();
    float* smS = (float*)&At[0][0];   // 128 cols x 8 contributors = 4 KB
    float* smQ = (float*)&Bt[0][0];
    int contrib = wr * 4 + (lane >> 4);
#pragma unroll
    for (int n = 0; n < 2; n++) {
        int col = wcq * 32 + n * 16 + l15;
        smS[col * 8 + contrib] = csum[n];
        smQ[col * 8 + contrib] = cssq[n];
    }
    __syncthreads();
    if (tid < 128) {
        float s = 0.f, q = 0.f;
#pragma unroll
        for (int i = 0; i < 8; i++) { s += smS[tid * 8 + i]; q += smQ[tid * 8 + i]; }
        atomicAdd(&stats[rel * 256 + tid], s);
        atomicAdd(&stats[rel * 256 + 128 + tid], q);
    }
}

// ---------------- BN stats (sum 16 replicas) -> affine (s,t); zero replicas ----------------

__global__ void finalize_kernel(float* __restrict__ statsR,
                                const float* __restrict__ gamma, const float* __restrict__ beta,
                                float* __restrict__ st) {
    int rel = blockIdx.x, c = threadIdx.x;
    float sum = 0.f, ssq = 0.f;
#pragma unroll
    for (int k = 0; k < SREP; k++) {
        sum += statsR[(size_t)k * 768 + rel * 256 + c];
        ssq += statsR[(size_t)k * 768 + rel * 256 + 128 + c];
        statsR[(size_t)k * 768 + rel * 256 + c] = 0.f;
        statsR[(size_t)k * 768 + rel * 256 + 128 + c] = 0.f;
    }
    const float invN = 1.f / N_NODES;
    float mu = sum * invN;
    float var = ssq * invN - mu * mu;
    float s = gamma[rel * H + c] * rsqrtf(var + EPS);
    st[rel * 2 * H + c] = s;
    st[rel * 2 * H + H + c] = beta[rel * H + c] - mu * s;
}

// ---------------- Weight prep (layers 2-4) ----------------

__global__ void prep_kernel(const float* __restrict__ Wself, const float* __restrict__ Wneigh,
                            const float* __restrict__ b, const float* __restrict__ st,
                            unsigned short* __restrict__ Wbt, float* __restrict__ biasp) {
    if (blockIdx.x < 384) {
        int idx = blockIdx.x * 256 + threadIdx.x;
        int rel = idx / (H * 256), rem = idx % (H * 256);
        int c = rem / 256, k = rem % 256;
        float v;
        if (k < 128) v = st[rel * 2 * H + k] * Wself[((size_t)rel * H + k) * H + c];
        else         v = Wneigh[((size_t)rel * H + (k - 128)) * H + c];
        Wbt[idx] = f2b(v);
    } else if (threadIdx.x < H) {
        int rel = blockIdx.x - 384, c = threadIdx.x;
        const float* t = st + rel * 2 * H + H;
        float s = b[rel * H + c];
        for (int k = 0; k < H; k++) s += t[k] * Wself[((size_t)rel * H + k) * H + c];
        biasp[rel * H + c] = s;
    }
}

// ---------------- Final: sum gout replicas, mean + BN affine ----------------

__global__ void scale_out_kernel(float* __restrict__ out, const float* __restrict__ goutR,
                                 const int* __restrict__ seg,
                                 const float* __restrict__ st_all) {
    int i = blockIdx.x * 256 + threadIdx.x;
    if (i >= GSZ) return;
    int g = i / (3 * 4 * H), k = i % (3 * 4 * H);
    int rel = k / (4 * H), rem = k % (4 * H), layer = rem / H, c = rem % H;
    const int* sg = seg + rel * N_NODES;
    int lo = 0, hi = N_NODES;
    while (lo < hi) { int m = (lo + hi) >> 1; if (sg[m] < g) lo = m + 1; else hi = m; }
    int start = lo;
    hi = N_NODES;
    while (lo < hi) { int m = (lo + hi) >> 1; if (sg[m] <= g) lo = m + 1; else hi = m; }
    int cnt = lo - start;
    float sum = 0.f;
#pragma unroll
    for (int r = 0; r < GREP; r++) sum += goutR[(size_t)r * GSZ + i];
    float mean = sum / (float)max(cnt, 1);
    const float* st = st_all + ((size_t)layer * 3 + rel) * 2 * H;
    out[i] = st[c] * mean + st[H + c];
}

// ---------------- Orchestration ----------------

extern "C" void kernel_launch(void* const* d_in, const int* in_sizes, int n_in,
                              void* d_out, int out_size, void* d_ws, size_t ws_size,
                              hipStream_t stream) {
    const int* h_idx = (const int*)d_in[0];
    const int* p_idx = (const int*)d_in[1];
    const int* hp_idx = (const int*)d_in[2];
    const int* src = (const int*)d_in[3];
    const int* dst = (const int*)d_in[4];
    const int* seg = (const int*)d_in[5];
    const float* emb_h = (const float*)d_in[6];
    const float* emb_p = (const float*)d_in[7];
    const float* emb_hp = (const float*)d_in[8];
    const float* W1_self = (const float*)d_in[9];
    const float* W1_neigh = (const float*)d_in[10];
    const float* b1 = (const float*)d_in[11];
    const float* a1 = (const float*)d_in[12];
    const float* gamma1 = (const float*)d_in[13];
    const float* beta1 = (const float*)d_in[14];
    const float* W_self = (const float*)d_in[15];
    const float* W_neigh = (const float*)d_in[16];
    const float* b = (const float*)d_in[17];
    const float* a = (const float*)d_in[18];
    const float* gamma = (const float*)d_in[19];
    const float* beta = (const float*)d_in[20];
    float* out = (float*)d_out;

    // workspace
    char* p = (char*)d_ws;
    unsigned short* hpA = (unsigned short*)p; p += (size_t)3 * N_NODES * H * 2;
    unsigned short* hpB = (unsigned short*)p; p += (size_t)3 * N_NODES * H * 2;
    unsigned short* Wbt1 = (unsigned short*)p; p += (size_t)3 * H * 128 * 2;
    unsigned short* Wbt = (unsigned short*)p; p += (size_t)3 * H * 256 * 2;
    unsigned short* emb_bf = (unsigned short*)p; p += (size_t)3 * 257 * EMB * 2;
    float* biasp = (float*)p; p += 3 * H * sizeof(float);
    float* st_all = (float*)p; p += 4 * 3 * 2 * H * sizeof(float);
    float* statsR = (float*)p; p += (size_t)SREP * 768 * sizeof(float);
    float* goutR = (float*)p; p += (size_t)GREP * GSZ * sizeof(float);
    int* deg = (int*)p; p += (size_t)3 * N_NODES * 4;
    int* row_ptr = (int*)p; p += (size_t)3 * (N_NODES + 1) * 4;
    int* cur = (int*)p; p += (size_t)3 * N_NODES * 4;
    int* gcur = (int*)p; p += (size_t)3 * NCH2 * 4;
    int* ctot = (int*)p; p += (size_t)3 * SCH * 4;
    int* edge_src = (int*)p; p += (size_t)3 * N_EDGES * 4;
    unsigned long long* chunkbuf = (unsigned long long*)p; p += (size_t)3 * N_EDGES * 8;

    hipMemsetAsync(statsR, 0, (size_t)SREP * 768 * 4, stream);
    hipMemsetAsync(goutR, 0, (size_t)GREP * GSZ * 4, stream);

    // CSR build: count -> 3-stage parallel scan -> partition -> place -> sort
    hipMemsetAsync(deg, 0, (size_t)3 * N_NODES * 4, stream);
    dim3 eb((N_EDGES + 255) / 256, 3);
    count_deg_kernel<<<eb, 256, 0, stream>>>(dst, deg);
    local_scan_kernel<<<dim3(SCH, 3), 1024, 0, stream>>>(deg, row_ptr, ctot);
    chunk_scan_kernel<<<3, 32, 0, stream>>>(ctot, row_ptr);
    fixup_kernel<<<(3 * N_NODES + 255) / 256, 256, 0, stream>>>(row_ptr, ctot, cur, gcur);
    partA_kernel<<<dim3(NSLA, 3), 256, 0, stream>>>(src, dst, gcur, chunkbuf);
    fillB_kernel<<<dim3(4 * NCH2, 3), 256, 0, stream>>>(row_ptr, chunkbuf, cur, edge_src);
    sort_adj_kernel<<<(3 * N_NODES + 255) / 256, 256, 0, stream>>>(row_ptr, edge_src);

    prep_init_kernel<<<217, 256, 0, stream>>>(W1_self, W1_neigh, Wbt1,
                                              emb_h, emb_p, emb_hp, emb_bf);

    dim3 gemm_grid((N_NODES + 127) / 128, 3);
    dim3 agg_grid((N_NODES + 31) / 32, 3);

    // ---- layer 1 (K = 64; nmean ld=64 in hpB via emb-table gather; out hpA) ----
    aggregate1_kernel<<<dim3((N_NODES + 31) / 32, 3), 256, 0, stream>>>(
        h_idx, p_idx, hp_idx, emb_bf, row_ptr, edge_src, hpB);
    gemm_kernel<64, true, true><<<gemm_grid, 512, 0, stream>>>(
        emb_bf /*unused*/, hpB, Wbt1, b1, a1, hpA, statsR, seg, goutR, 0,
        emb_bf, h_idx, p_idx, hp_idx);
    finalize_kernel<<<3, H, 0, stream>>>(statsR, gamma1, beta1, st_all);

    // ---- layers 2-4 (K = 128; out aliases nmean; last layer skips hp store) ----
    unsigned short* xin = hpA;
    unsigned short* xout = hpB;
    for (int l = 0; l < 3; l++) {
        const float* st_prev = st_all + (size_t)l * 3 * 2 * H;
        prep_kernel<<<387, 256, 0, stream>>>(
            W_self + (size_t)l * 3 * H * H, W_neigh + (size_t)l * 3 * H * H,
            b + (size_t)l * 3 * H, st_prev, Wbt, biasp);
        aggregate_kernel<true><<<agg_grid, 256, 0, stream>>>(
            xin, row_ptr, edge_src, st_prev, xout);
        if (l < 2)
            gemm_kernel<128, false, true><<<gemm_grid, 512, 0, stream>>>(
                xin, xout, Wbt, biasp, a + (size_t)l * 3 * H, xout, statsR, seg, goutR, l + 1,
                nullptr, nullptr, nullptr, nullptr);
        else
            gemm_kernel<128, false, false><<<gemm_grid, 512, 0, stream>>>(
                xin, xout, Wbt, biasp, a + (size_t)l * 3 * H, xout, statsR, seg, goutR, l + 1,
                nullptr, nullptr, nullptr, nullptr);
        finalize_kernel<<<3, H, 0, stream>>>(
            statsR, gamma + (size_t)l * 3 * H, beta + (size_t)l * 3 * H,
            st_all + (size_t)(l + 1) * 3 * 2 * H);
        unsigned short* t = xin; xin = xout; xout = t;
    }

    scale_out_kernel<<<(GSZ + 255) / 256, 256, 0, stream>>>(out, goutR, seg, st_all);
}